// Round 1
// baseline (986.507 us; speedup 1.0000x reference)
//
#include <hip/hip_runtime.h>
#include <hip/hip_bf16.h>

// Problem constants
#define BB 32   // batch
#define TT 32   // window
#define NN 64   // num_series
#define CC 64   // inter_dim
#define HH 64   // gru hidden
#define QKD 32  // qk dim
#define HOR 12
#define OUTD (NN*HOR)        // 768
#define KFLAT (NN*CC*TT)     // 131072

// ---------------- GRU: one wave (64 lanes) per series, 4 series/block -------
__global__ __launch_bounds__(256) void gru_kernel(
    const float* __restrict__ x, const float* __restrict__ wih,
    const float* __restrict__ whh, const float* __restrict__ bih,
    const float* __restrict__ bhh, float* __restrict__ hT)
{
    __shared__ float Wt[64][192];   // Wt[k][g] = whh[g][k]  (48 KB)
    __shared__ float hbuf[4][64];
    int tid = threadIdx.x;
    for (int idx = tid; idx < 192*64; idx += 256) {
        int g = idx >> 6, k = idx & 63;
        Wt[k][g] = whh[idx];
    }
    int ls = tid >> 6;            // local series 0..3 (one wave each)
    int j  = tid & 63;            // hidden index
    int gs = blockIdx.x * 4 + ls; // global series = b*NN + n
    int b = gs >> 6, n = gs & 63;
    hbuf[ls][j] = 0.0f;
    __syncthreads();
    float wih_r = wih[j], wih_z = wih[64+j], wih_n = wih[128+j];
    float bi_r = bih[j], bi_z = bih[64+j], bi_n = bih[128+j];
    float bh_r = bhh[j], bh_z = bhh[64+j], bh_n = bhh[128+j];
    for (int t = 0; t < TT; ++t) {
        float xt = x[(b*TT + t)*NN + n];
        float gr = bh_r, gz = bh_z, gn = bh_n;
        #pragma unroll 8
        for (int k = 0; k < 64; ++k) {
            float hk = hbuf[ls][k];
            gr += hk * Wt[k][j];
            gz += hk * Wt[k][64+j];
            gn += hk * Wt[k][128+j];
        }
        float gir = xt*wih_r + bi_r;
        float giz = xt*wih_z + bi_z;
        float gin = xt*wih_n + bi_n;
        float r = 1.f/(1.f+__expf(-(gir+gr)));
        float z = 1.f/(1.f+__expf(-(giz+gz)));
        float nn = tanhf(gin + r*gn);
        float hnew = (1.f - z)*nn + z*hbuf[ls][j];
        __syncthreads();
        hbuf[ls][j] = hnew;
        __syncthreads();
    }
    hT[gs*64 + j] = hbuf[ls][j];
}

// ---------------- attention -> normalized adjacency What (per batch) --------
__global__ __launch_bounds__(256) void attn_kernel(
    const float* __restrict__ hT, const float* __restrict__ wq_w,
    const float* __restrict__ wq_b, const float* __restrict__ wk_w,
    const float* __restrict__ wk_b, float* __restrict__ What)
{
    __shared__ float hs[64][64];
    __shared__ float Qs[64][32], Ks[64][32];
    __shared__ float S[64][64];
    __shared__ float dinv[64];
    int b = blockIdx.x, tid = threadIdx.x;
    for (int idx = tid; idx < 64*64; idx += 256) hs[idx>>6][idx&63] = hT[b*4096 + idx];
    __syncthreads();
    for (int idx = tid; idx < 64*32; idx += 256) {
        int n_ = idx >> 5, q = idx & 31;
        float accq = wq_b[q], acck = wk_b[q];
        #pragma unroll 8
        for (int h_ = 0; h_ < 64; ++h_) {
            float hv = hs[n_][h_];
            accq += hv * wq_w[q*64 + h_];
            acck += hv * wk_w[q*64 + h_];
        }
        Qs[n_][q] = accq; Ks[n_][q] = acck;
    }
    __syncthreads();
    const float scale = 0.17677669529663687f; // 1/sqrt(32)
    for (int idx = tid; idx < 64*64; idx += 256) {
        int n_ = idx >> 6, m = idx & 63;
        float acc = 0.f;
        #pragma unroll 8
        for (int q = 0; q < 32; ++q) acc += Qs[n_][q]*Ks[m][q];
        S[n_][m] = acc * scale;
    }
    __syncthreads();
    if (tid < 64) {  // row softmax
        float mx = -1e30f;
        for (int m = 0; m < 64; ++m) mx = fmaxf(mx, S[tid][m]);
        float sum = 0.f;
        for (int m = 0; m < 64; ++m) { float e = __expf(S[tid][m]-mx); S[tid][m] = e; sum += e; }
        float inv = 1.f/sum;
        for (int m = 0; m < 64; ++m) S[tid][m] *= inv;
    }
    __syncthreads();
    if (tid < 64) {  // column degree
        float d = 0.f;
        for (int n_ = 0; n_ < 64; ++n_) d += S[n_][tid];
        dinv[tid] = (d > 0.f) ? 1.0f/sqrtf(d) : 0.f;
    }
    __syncthreads();
    for (int idx = tid; idx < 64*64; idx += 256) {
        int n_ = idx >> 6, m = idx & 63;
        What[b*4096 + idx] = dinv[n_]*S[n_][m]*dinv[m];
    }
}

// ---------------- feats init: x_to_inter_dim (1x1 conv) --------------------
__global__ void feats_init(const float* __restrict__ x, const float* __restrict__ w,
                           const float* __restrict__ bb, float* __restrict__ f)
{
    int idx = blockIdx.x*256 + threadIdx.x;   // T*B*N*C = 4194304
    int c = idx & 63;
    int tbn = idx >> 6;
    int n = tbn & 63;
    int tb = tbn >> 6;
    int b = tb & 31;
    int t = tb >> 5;
    f[idx] = x[(b*TT + t)*NN + n] * w[c] + bb[c];
}

// ---------------- per-timestep GCN theta matmul: (N,C)@(C,C) per (t,b) -----
__global__ __launch_bounds__(256) void xw_kernel(const float* __restrict__ f,
                                                 const float* __restrict__ gw,
                                                 float* __restrict__ xw)
{
    __shared__ float ft[64][64];
    __shared__ float gt[64][64];
    int tb = blockIdx.x;           // t*BB + b
    int t = tb >> 5;
    const float* fin = f + (size_t)tb*4096;
    const float* gwt = gw + (size_t)t*4096;
    int tid = threadIdx.x;
    for (int idx = tid; idx < 4096; idx += 256) {
        ft[idx>>6][idx&63] = fin[idx];
        gt[idx>>6][idx&63] = gwt[idx];
    }
    __syncthreads();
    int d = tid & 63, ty = tid >> 6;
    float* xout = xw + (size_t)tb*4096;
    for (int n0 = 0; n0 < 16; ++n0) {
        int n_ = ty*16 + n0;
        float acc = 0.f;
        #pragma unroll 8
        for (int c = 0; c < 64; ++c) acc += ft[n_][c]*gt[c][d];
        xout[n_*64 + d] = acc;
    }
}

// ---------------- graph aggregation (in-place): agg[j] = sum_i What[i][j]x[i]
__global__ __launch_bounds__(256) void agg_kernel(float* __restrict__ xw,
                                                  const float* __restrict__ What,
                                                  const float* __restrict__ gb)
{
    __shared__ float xt[64][64];
    __shared__ float wt[64][64];
    int tb = blockIdx.x;
    int t = tb >> 5, b = tb & 31;
    float* xin = xw + (size_t)tb*4096;
    const float* wb = What + (size_t)b*4096;
    int tid = threadIdx.x;
    for (int idx = tid; idx < 4096; idx += 256) {
        xt[idx>>6][idx&63] = xin[idx];
        wt[idx>>6][idx&63] = wb[idx];
    }
    __syncthreads();
    int d = tid & 63, ty = tid >> 6;
    const float* gbt = gb + t*64;
    for (int j0 = 0; j0 < 16; ++j0) {
        int j = ty*16 + j0;
        float acc = gbt[d];
        #pragma unroll 8
        for (int i = 0; i < 64; ++i) acc += wt[i][j]*xt[i][d];
        xin[j*64 + d] = acc;
    }
}

// ---------------- temporal conv1d + LeakyReLU (in-place per (b,n)) ---------
template<int KW>
__global__ __launch_bounds__(256) void conv_kernel(float* __restrict__ g,
                                                   const float* __restrict__ cw,
                                                   const float* __restrict__ cb)
{
    constexpr int P = KW/2;
    __shared__ float seq[32][64];         // [t][ci]
    __shared__ float wls[16*KW*64];       // [ci_l][kappa][co]
    int bn = blockIdx.x;                  // b*NN + n
    int tid = threadIdx.x;
    for (int idx = tid; idx < 32*64; idx += 256) {
        int t = idx >> 6, ci = idx & 63;
        seq[t][ci] = g[((size_t)(t*2048) + bn)*64 + ci];
    }
    int co = tid & 63, tg = tid >> 6;     // tg -> 8 consecutive t's
    float acc[8];
    #pragma unroll
    for (int i = 0; i < 8; ++i) acc[i] = cb[co];
    for (int cc = 0; cc < 4; ++cc) {
        __syncthreads();
        for (int idx = tid; idx < 16*KW*64; idx += 256) {
            int co_ = idx & 63;
            int rest = idx >> 6;          // ci_l*KW + kappa
            int ka = rest % KW, ci_l = rest / KW;
            wls[idx] = cw[((size_t)co_*64 + cc*16 + ci_l)*KW + ka];
        }
        __syncthreads();
        for (int ci_l = 0; ci_l < 16; ++ci_l) {
            int ci = cc*16 + ci_l;
            float rv[8 + 2*P];
            #pragma unroll
            for (int u = 0; u < 8 + 2*P; ++u) {
                int ts = tg*8 + u - P;
                rv[u] = (ts >= 0 && ts < 32) ? seq[ts][ci] : 0.f;
            }
            #pragma unroll
            for (int ka = 0; ka < KW; ++ka) {
                float w = wls[(ci_l*KW + ka)*64 + co];
                #pragma unroll
                for (int tt = 0; tt < 8; ++tt) acc[tt] += rv[tt + ka] * w;
            }
        }
    }
    __syncthreads();
    #pragma unroll
    for (int tt = 0; tt < 8; ++tt) {
        int t = tg*8 + tt;
        float v = acc[tt];
        v = (v >= 0.f) ? v : 0.01f*v;
        g[((size_t)(t*2048) + bn)*64 + co] = v;
    }
}

// ---------------- transpose feats (T,B,N,C) -> flat (B, n*C*T + c*T + t) ---
__global__ void transpose_kernel(const float* __restrict__ f, float* __restrict__ o)
{
    __shared__ float tl[32][65];
    int bn = blockIdx.x;                  // b*NN + n
    int tid = threadIdx.x;
    for (int idx = tid; idx < 2048; idx += 256) {
        int t = idx >> 6, c = idx & 63;
        tl[t][c] = f[((size_t)t*2048 + bn)*64 + c];
    }
    __syncthreads();
    int b = bn >> 6, n = bn & 63;
    float* ob = o + (size_t)b*KFLAT + n*2048;
    for (int idx = tid; idx < 2048; idx += 256) {
        int c = idx >> 5, t = idx & 31;
        ob[c*32 + t] = tl[t][c];
    }
}

// ---------------- output init with bias ------------------------------------
__global__ void out_init(const float* __restrict__ bias, float* __restrict__ out)
{
    int idx = blockIdx.x*256 + threadIdx.x;   // 24576
    out[idx] = bias[idx % OUTD];
}

// ---------------- final GEMM: out[b,o] += sum_k flat[b,k]*W[o,k] -----------
// grid: 24 o-groups (32 o each) x 64 k-chunks (2048 each) = 1536 blocks
__global__ __launch_bounds__(256) void gemm_kernel(const float* __restrict__ flat,
                                                   const float* __restrict__ W,
                                                   float* __restrict__ out)
{
    __shared__ float wt[32][65];
    __shared__ float ftl[32][65];
    int og = blockIdx.x % 24;
    int kc = blockIdx.x / 24;
    int o0 = og*32;
    int k0 = kc*2048;
    int tid = threadIdx.x;
    int tx = tid & 31;   // o offset
    int ty = tid >> 5;   // 0..7 -> batches {ty, ty+8, ty+16, ty+24}
    float acc0=0.f, acc1=0.f, acc2=0.f, acc3=0.f;
    for (int kk = 0; kk < 2048; kk += 64) {
        __syncthreads();
        for (int idx = tid; idx < 2048; idx += 256) {
            int oo = idx >> 6, kj = idx & 63;
            wt[oo][kj]  = W[(size_t)(o0+oo)*KFLAT + k0+kk+kj];
            ftl[oo][kj] = flat[(size_t)oo*KFLAT + k0+kk+kj];
        }
        __syncthreads();
        #pragma unroll 8
        for (int j = 0; j < 64; ++j) {
            float w = wt[tx][j];
            acc0 += ftl[ty   ][j]*w;
            acc1 += ftl[ty+8 ][j]*w;
            acc2 += ftl[ty+16][j]*w;
            acc3 += ftl[ty+24][j]*w;
        }
    }
    atomicAdd(&out[(size_t)(ty   )*OUTD + o0+tx], acc0);
    atomicAdd(&out[(size_t)(ty+8 )*OUTD + o0+tx], acc1);
    atomicAdd(&out[(size_t)(ty+16)*OUTD + o0+tx], acc2);
    atomicAdd(&out[(size_t)(ty+24)*OUTD + o0+tx], acc3);
}

extern "C" void kernel_launch(void* const* d_in, const int* in_sizes, int n_in,
                              void* d_out, int out_size, void* d_ws, size_t ws_size,
                              hipStream_t stream) {
    (void)in_sizes; (void)n_in; (void)out_size; (void)ws_size;
    const float* x        = (const float*)d_in[0];
    const float* w_x2i    = (const float*)d_in[1];
    const float* b_x2i    = (const float*)d_in[2];
    const float* gru_wih  = (const float*)d_in[3];
    const float* gru_whh  = (const float*)d_in[4];
    const float* gru_bih  = (const float*)d_in[5];
    const float* gru_bhh  = (const float*)d_in[6];
    const float* wq_w     = (const float*)d_in[7];
    const float* wq_b     = (const float*)d_in[8];
    const float* wk_w     = (const float*)d_in[9];
    const float* wk_b     = (const float*)d_in[10];
    const float* gcn_w[3]  = {(const float*)d_in[11], (const float*)d_in[15], (const float*)d_in[19]};
    const float* gcn_b[3]  = {(const float*)d_in[12], (const float*)d_in[16], (const float*)d_in[20]};
    const float* conv_w[3] = {(const float*)d_in[13], (const float*)d_in[17], (const float*)d_in[21]};
    const float* conv_b[3] = {(const float*)d_in[14], (const float*)d_in[18], (const float*)d_in[22]};
    const float* lout_w   = (const float*)d_in[23];
    const float* lout_b   = (const float*)d_in[24];
    float* out = (float*)d_out;
    float* ws  = (float*)d_ws;

    float* hT   = ws;                    // 131072
    float* What = ws + 131072;           // 131072
    float* bufA = ws + 262144;           // 4194304
    float* bufB = bufA + 4194304;        // 4194304

    gru_kernel<<<dim3(512), dim3(256), 0, stream>>>(x, gru_wih, gru_whh, gru_bih, gru_bhh, hT);
    attn_kernel<<<dim3(32), dim3(256), 0, stream>>>(hT, wq_w, wq_b, wk_w, wk_b, What);
    feats_init<<<dim3(16384), dim3(256), 0, stream>>>(x, w_x2i, b_x2i, bufA);

    float* cur = bufA; float* oth = bufB;
    for (int i = 0; i < 3; ++i) {
        xw_kernel<<<dim3(1024), dim3(256), 0, stream>>>(cur, gcn_w[i], oth);
        agg_kernel<<<dim3(1024), dim3(256), 0, stream>>>(oth, What, gcn_b[i]);
        if (i == 0) conv_kernel<3><<<dim3(2048), dim3(256), 0, stream>>>(oth, conv_w[i], conv_b[i]);
        if (i == 1) conv_kernel<5><<<dim3(2048), dim3(256), 0, stream>>>(oth, conv_w[i], conv_b[i]);
        if (i == 2) conv_kernel<7><<<dim3(2048), dim3(256), 0, stream>>>(oth, conv_w[i], conv_b[i]);
        float* tmp = cur; cur = oth; oth = tmp;
    }
    transpose_kernel<<<dim3(2048), dim3(256), 0, stream>>>(cur, oth);
    out_init<<<dim3(96), dim3(256), 0, stream>>>(lout_b, out);
    gemm_kernel<<<dim3(1536), dim3(256), 0, stream>>>(oth, lout_w, out);
}

// Round 2
// 860.384 us; speedup vs baseline: 1.1466x; 1.1466x over previous
//
#include <hip/hip_runtime.h>
#include <hip/hip_bf16.h>

// Problem constants
#define BB 32   // batch
#define TT 32   // window
#define NN 64   // num_series
#define CC 64   // inter_dim
#define HH 64   // gru hidden
#define QKD 32  // qk dim
#define HOR 12
#define OUTD (NN*HOR)        // 768
#define KFLAT (NN*CC*TT)     // 131072

// ---------------- GRU: one wave (64 lanes) per series, 4 series/block -------
__global__ __launch_bounds__(256) void gru_kernel(
    const float* __restrict__ x, const float* __restrict__ wih,
    const float* __restrict__ whh, const float* __restrict__ bih,
    const float* __restrict__ bhh, float* __restrict__ hT)
{
    __shared__ float Wt[64][192];   // Wt[k][g] = whh[g][k]  (48 KB)
    __shared__ float hbuf[4][64];
    int tid = threadIdx.x;
    for (int idx = tid; idx < 192*64; idx += 256) {
        int g = idx >> 6, k = idx & 63;
        Wt[k][g] = whh[idx];
    }
    int ls = tid >> 6;            // local series 0..3 (one wave each)
    int j  = tid & 63;            // hidden index
    int gs = blockIdx.x * 4 + ls; // global series = b*NN + n
    int b = gs >> 6, n = gs & 63;
    hbuf[ls][j] = 0.0f;
    __syncthreads();
    float wih_r = wih[j], wih_z = wih[64+j], wih_n = wih[128+j];
    float bi_r = bih[j], bi_z = bih[64+j], bi_n = bih[128+j];
    float bh_r = bhh[j], bh_z = bhh[64+j], bh_n = bhh[128+j];
    for (int t = 0; t < TT; ++t) {
        float xt = x[(b*TT + t)*NN + n];
        float gr = bh_r, gz = bh_z, gn = bh_n;
        #pragma unroll 8
        for (int k = 0; k < 64; ++k) {
            float hk = hbuf[ls][k];
            gr += hk * Wt[k][j];
            gz += hk * Wt[k][64+j];
            gn += hk * Wt[k][128+j];
        }
        float gir = xt*wih_r + bi_r;
        float giz = xt*wih_z + bi_z;
        float gin = xt*wih_n + bi_n;
        float r = 1.f/(1.f+__expf(-(gir+gr)));
        float z = 1.f/(1.f+__expf(-(giz+gz)));
        float nn = tanhf(gin + r*gn);
        float hnew = (1.f - z)*nn + z*hbuf[ls][j];
        __syncthreads();
        hbuf[ls][j] = hnew;
        __syncthreads();
    }
    hT[gs*64 + j] = hbuf[ls][j];
}

// ---------------- attention -> normalized adjacency What (per batch) --------
__global__ __launch_bounds__(256) void attn_kernel(
    const float* __restrict__ hT, const float* __restrict__ wq_w,
    const float* __restrict__ wq_b, const float* __restrict__ wk_w,
    const float* __restrict__ wk_b, float* __restrict__ What)
{
    __shared__ float hs[64][64];
    __shared__ float Qs[64][32], Ks[64][32];
    __shared__ float S[64][64];
    __shared__ float dinv[64];
    int b = blockIdx.x, tid = threadIdx.x;
    for (int idx = tid; idx < 64*64; idx += 256) hs[idx>>6][idx&63] = hT[b*4096 + idx];
    __syncthreads();
    for (int idx = tid; idx < 64*32; idx += 256) {
        int n_ = idx >> 5, q = idx & 31;
        float accq = wq_b[q], acck = wk_b[q];
        #pragma unroll 8
        for (int h_ = 0; h_ < 64; ++h_) {
            float hv = hs[n_][h_];
            accq += hv * wq_w[q*64 + h_];
            acck += hv * wk_w[q*64 + h_];
        }
        Qs[n_][q] = accq; Ks[n_][q] = acck;
    }
    __syncthreads();
    const float scale = 0.17677669529663687f; // 1/sqrt(32)
    for (int idx = tid; idx < 64*64; idx += 256) {
        int n_ = idx >> 6, m = idx & 63;
        float acc = 0.f;
        #pragma unroll 8
        for (int q = 0; q < 32; ++q) acc += Qs[n_][q]*Ks[m][q];
        S[n_][m] = acc * scale;
    }
    __syncthreads();
    if (tid < 64) {  // row softmax
        float mx = -1e30f;
        for (int m = 0; m < 64; ++m) mx = fmaxf(mx, S[tid][m]);
        float sum = 0.f;
        for (int m = 0; m < 64; ++m) { float e = __expf(S[tid][m]-mx); S[tid][m] = e; sum += e; }
        float inv = 1.f/sum;
        for (int m = 0; m < 64; ++m) S[tid][m] *= inv;
    }
    __syncthreads();
    if (tid < 64) {  // column degree
        float d = 0.f;
        for (int n_ = 0; n_ < 64; ++n_) d += S[n_][tid];
        dinv[tid] = (d > 0.f) ? 1.0f/sqrtf(d) : 0.f;
    }
    __syncthreads();
    for (int idx = tid; idx < 64*64; idx += 256) {
        int n_ = idx >> 6, m = idx & 63;
        What[b*4096 + idx] = dinv[n_]*S[n_][m]*dinv[m];
    }
}

// ---------------- feats init: x_to_inter_dim (1x1 conv) --------------------
__global__ void feats_init(const float* __restrict__ x, const float* __restrict__ w,
                           const float* __restrict__ bb, float* __restrict__ f)
{
    int idx = blockIdx.x*256 + threadIdx.x;   // T*B*N*C = 4194304
    int c = idx & 63;
    int tbn = idx >> 6;
    int n = tbn & 63;
    int tb = tbn >> 6;
    int b = tb & 31;
    int t = tb >> 5;
    f[idx] = x[(b*TT + t)*NN + n] * w[c] + bb[c];
}

// ---------------- fused GCN theta matmul + graph aggregation per (t,b) -----
// xs[n][d] = sum_c ft[n][c]*gw[t][c][d];  out[j][d] = gb[t][d] + sum_i What[b][i][j]*xs[i][d]
__global__ __launch_bounds__(256) void gcn_kernel(const float* __restrict__ f,
    const float* __restrict__ gw, const float* __restrict__ What,
    const float* __restrict__ gb, float* __restrict__ o)
{
    __shared__ __align__(16) float ft[64][64];
    __shared__ __align__(16) float wt[64][64];
    __shared__ float xs[64][64];
    int tb = blockIdx.x, t = tb >> 5, b = tb & 31;
    int tid = threadIdx.x, d = tid & 63, ty = tid >> 6;
    const float* fin = f + (size_t)tb*4096;
    const float* wb  = What + (size_t)b*4096;
    for (int idx = tid; idx < 4096; idx += 256) {
        ft[idx>>6][idx&63] = fin[idx];
        wt[idx>>6][idx&63] = wb[idx];
    }
    // per-thread copy of gw[t][:, d] (column for this lane's output channel)
    float g[64];
    const float* gwt = gw + (size_t)t*4096;
    #pragma unroll
    for (int c = 0; c < 64; ++c) g[c] = gwt[c*64 + d];
    __syncthreads();
    {   // xw phase: rows n = ty*16 .. ty*16+15
        float acc[16];
        #pragma unroll
        for (int i = 0; i < 16; ++i) acc[i] = 0.f;
        #pragma unroll
        for (int c4 = 0; c4 < 16; ++c4) {
            #pragma unroll
            for (int i = 0; i < 16; ++i) {
                const float4 fv = *(const float4*)&ft[ty*16 + i][c4*4];
                acc[i] += fv.x*g[4*c4] + fv.y*g[4*c4+1] + fv.z*g[4*c4+2] + fv.w*g[4*c4+3];
            }
        }
        #pragma unroll
        for (int i = 0; i < 16; ++i) xs[ty*16 + i][d] = acc[i];
    }
    __syncthreads();
    {   // agg phase: cols j = ty*16 .. ty*16+15
        float acc[16];
        float bias = gb[t*64 + d];
        #pragma unroll
        for (int i = 0; i < 16; ++i) acc[i] = bias;
        for (int i2 = 0; i2 < 64; ++i2) {
            float xv = xs[i2][d];
            #pragma unroll
            for (int jj = 0; jj < 4; ++jj) {
                const float4 wv = *(const float4*)&wt[i2][ty*16 + jj*4];
                acc[jj*4+0] += wv.x*xv; acc[jj*4+1] += wv.y*xv;
                acc[jj*4+2] += wv.z*xv; acc[jj*4+3] += wv.w*xv;
            }
        }
        float* oo = o + (size_t)tb*4096;
        #pragma unroll
        for (int i = 0; i < 16; ++i) oo[(ty*16 + i)*64 + d] = acc[i];
    }
}

// ---------------- temporal conv1d + LeakyReLU (in-place per (b,n)) ---------
template<int KW>
__global__ __launch_bounds__(256) void conv_kernel(float* __restrict__ g,
                                                   const float* __restrict__ cw,
                                                   const float* __restrict__ cb)
{
    constexpr int P = KW/2;
    __shared__ float seq[32][64];         // [t][ci]
    __shared__ float wls[16*KW*64];       // [ci_l][kappa][co]
    int bn = blockIdx.x;                  // b*NN + n
    int tid = threadIdx.x;
    for (int idx = tid; idx < 32*64; idx += 256) {
        int t = idx >> 6, ci = idx & 63;
        seq[t][ci] = g[((size_t)(t*2048) + bn)*64 + ci];
    }
    int co = tid & 63, tg = tid >> 6;     // tg -> 8 consecutive t's
    float acc[8];
    #pragma unroll
    for (int i = 0; i < 8; ++i) acc[i] = cb[co];
    for (int cc = 0; cc < 4; ++cc) {
        __syncthreads();
        for (int idx = tid; idx < 16*KW*64; idx += 256) {
            int co_ = idx & 63;
            int rest = idx >> 6;          // ci_l*KW + kappa
            int ka = rest % KW, ci_l = rest / KW;
            wls[idx] = cw[((size_t)co_*64 + cc*16 + ci_l)*KW + ka];
        }
        __syncthreads();
        for (int ci_l = 0; ci_l < 16; ++ci_l) {
            int ci = cc*16 + ci_l;
            float rv[8 + 2*P];
            #pragma unroll
            for (int u = 0; u < 8 + 2*P; ++u) {
                int ts = tg*8 + u - P;
                rv[u] = (ts >= 0 && ts < 32) ? seq[ts][ci] : 0.f;
            }
            #pragma unroll
            for (int ka = 0; ka < KW; ++ka) {
                float w = wls[(ci_l*KW + ka)*64 + co];
                #pragma unroll
                for (int tt = 0; tt < 8; ++tt) acc[tt] += rv[tt + ka] * w;
            }
        }
    }
    __syncthreads();
    #pragma unroll
    for (int tt = 0; tt < 8; ++tt) {
        int t = tg*8 + tt;
        float v = acc[tt];
        v = (v >= 0.f) ? v : 0.01f*v;
        g[((size_t)(t*2048) + bn)*64 + co] = v;
    }
}

// ---------------- transpose feats (T,B,N,C) -> flat (B, n*C*T + c*T + t) ---
__global__ void transpose_kernel(const float* __restrict__ f, float* __restrict__ o)
{
    __shared__ float tl[32][65];
    int bn = blockIdx.x;                  // b*NN + n
    int tid = threadIdx.x;
    for (int idx = tid; idx < 2048; idx += 256) {
        int t = idx >> 6, c = idx & 63;
        tl[t][c] = f[((size_t)t*2048 + bn)*64 + c];
    }
    __syncthreads();
    int b = bn >> 6, n = bn & 63;
    float* ob = o + (size_t)b*KFLAT + n*2048;
    for (int idx = tid; idx < 2048; idx += 256) {
        int c = idx >> 5, t = idx & 31;
        ob[c*32 + t] = tl[t][c];
    }
}

// ---------------- output init with bias ------------------------------------
__global__ void out_init(const float* __restrict__ bias, float* __restrict__ out)
{
    int idx = blockIdx.x*256 + threadIdx.x;   // 24576
    out[idx] = bias[idx % OUTD];
}

// ---------------- final GEMM: out[b,o] += sum_k flat[b,k]*W[o,k] -----------
// Register-blocked streaming GEMM. Grid: 48 o-groups x 16 k-chunks = 768.
// bid = og*16 + kc so all blocks of one kc land on XCD kc%8 (flat L2-resident).
// Each wave: 4 o-rows, acc[4][32] in VGPRs; lane owns a float4 k-stripe;
// W streamed global->reg (coalesced, read exactly once); flat tile in LDS
// double-buffered; cross-lane butterfly reduce + 16-way atomic at the end.
__global__ __launch_bounds__(256, 2) void gemm_kernel(const float* __restrict__ flat,
                                                      const float* __restrict__ W,
                                                      float* __restrict__ out)
{
    __shared__ __align__(16) float fl[2][32][256];   // 64 KB
    __shared__ float red[4][128];
    int og = blockIdx.x >> 4;
    int kc = blockIdx.x & 15;
    int kbase = kc * 8192;
    int tid = threadIdx.x;
    int w = tid >> 6;        // wave id 0..3
    int lane = tid & 63;
    int o0 = og*16 + w*4;

    const float4* fp4 = (const float4*)flat;

#define STAGE(buf, k0s) { \
    int idx_ = tid; \
    _Pragma("unroll") \
    for (int it_ = 0; it_ < 8; ++it_, idx_ += 256) { \
        int b_ = idx_ >> 6, c4_ = idx_ & 63; \
        *(float4*)&buf[b_][c4_*4] = fp4[(size_t)b_*(KFLAT/4) + ((k0s)>>2) + c4_]; \
    } }

    float acc[4][32];
    #pragma unroll
    for (int r = 0; r < 4; ++r)
        #pragma unroll
        for (int b2 = 0; b2 < 32; ++b2) acc[r][b2] = 0.f;

    // prologue: stage step 0, prefetch W for step 0
    STAGE(fl[0], kbase);
    float4 w4[4], w4n[4];
    #pragma unroll
    for (int r = 0; r < 4; ++r)
        w4[r] = *(const float4*)&W[(size_t)(o0 + r)*KFLAT + kbase + lane*4];

    int cur = 0;
    for (int s = 0; s < 32; ++s) {
        __syncthreads();            // fl[cur] staged; prev compute done
        if (s < 31) {
            STAGE(fl[cur^1], kbase + (s+1)*256);
            #pragma unroll
            for (int r = 0; r < 4; ++r)
                w4n[r] = *(const float4*)&W[(size_t)(o0 + r)*KFLAT + kbase + (s+1)*256 + lane*4];
        }
        #pragma unroll
        for (int b2 = 0; b2 < 32; ++b2) {
            const float4 f4 = *(const float4*)&fl[cur][b2][lane*4];
            #pragma unroll
            for (int r = 0; r < 4; ++r) {
                acc[r][b2] += w4[r].x*f4.x + w4[r].y*f4.y + w4[r].z*f4.z + w4[r].w*f4.w;
            }
        }
        #pragma unroll
        for (int r = 0; r < 4; ++r) w4[r] = w4n[r];
        cur ^= 1;
    }
#undef STAGE

    // cross-lane reduce (each lane held a disjoint k-stripe)
    #pragma unroll
    for (int r = 0; r < 4; ++r) {
        #pragma unroll
        for (int b2 = 0; b2 < 32; ++b2) {
            float v = acc[r][b2];
            v += __shfl_xor(v, 1);
            v += __shfl_xor(v, 2);
            v += __shfl_xor(v, 4);
            v += __shfl_xor(v, 8);
            v += __shfl_xor(v, 16);
            v += __shfl_xor(v, 32);
            if (lane == 0) red[w][r*32 + b2] = v;
        }
    }
    #pragma unroll
    for (int i = 0; i < 2; ++i) {
        int idx = lane*2 + i;           // 0..127
        int r = idx >> 5, b2 = idx & 31;
        atomicAdd(&out[(size_t)b2*OUTD + o0 + r], red[w][idx]);
    }
}

extern "C" void kernel_launch(void* const* d_in, const int* in_sizes, int n_in,
                              void* d_out, int out_size, void* d_ws, size_t ws_size,
                              hipStream_t stream) {
    (void)in_sizes; (void)n_in; (void)out_size; (void)ws_size;
    const float* x        = (const float*)d_in[0];
    const float* w_x2i    = (const float*)d_in[1];
    const float* b_x2i    = (const float*)d_in[2];
    const float* gru_wih  = (const float*)d_in[3];
    const float* gru_whh  = (const float*)d_in[4];
    const float* gru_bih  = (const float*)d_in[5];
    const float* gru_bhh  = (const float*)d_in[6];
    const float* wq_w     = (const float*)d_in[7];
    const float* wq_b     = (const float*)d_in[8];
    const float* wk_w     = (const float*)d_in[9];
    const float* wk_b     = (const float*)d_in[10];
    const float* gcn_w[3]  = {(const float*)d_in[11], (const float*)d_in[15], (const float*)d_in[19]};
    const float* gcn_b[3]  = {(const float*)d_in[12], (const float*)d_in[16], (const float*)d_in[20]};
    const float* conv_w[3] = {(const float*)d_in[13], (const float*)d_in[17], (const float*)d_in[21]};
    const float* conv_b[3] = {(const float*)d_in[14], (const float*)d_in[18], (const float*)d_in[22]};
    const float* lout_w   = (const float*)d_in[23];
    const float* lout_b   = (const float*)d_in[24];
    float* out = (float*)d_out;
    float* ws  = (float*)d_ws;

    float* hT   = ws;                    // 131072
    float* What = ws + 131072;           // 131072
    float* bufA = ws + 262144;           // 4194304
    float* bufB = bufA + 4194304;        // 4194304

    gru_kernel<<<dim3(512), dim3(256), 0, stream>>>(x, gru_wih, gru_whh, gru_bih, gru_bhh, hT);
    attn_kernel<<<dim3(32), dim3(256), 0, stream>>>(hT, wq_w, wq_b, wk_w, wk_b, What);
    feats_init<<<dim3(16384), dim3(256), 0, stream>>>(x, w_x2i, b_x2i, bufA);

    float* cur = bufA; float* oth = bufB;
    for (int i = 0; i < 3; ++i) {
        gcn_kernel<<<dim3(1024), dim3(256), 0, stream>>>(cur, gcn_w[i], What, gcn_b[i], oth);
        if (i == 0) conv_kernel<3><<<dim3(2048), dim3(256), 0, stream>>>(oth, conv_w[i], conv_b[i]);
        if (i == 1) conv_kernel<5><<<dim3(2048), dim3(256), 0, stream>>>(oth, conv_w[i], conv_b[i]);
        if (i == 2) conv_kernel<7><<<dim3(2048), dim3(256), 0, stream>>>(oth, conv_w[i], conv_b[i]);
        float* tmp = cur; cur = oth; oth = tmp;
    }
    transpose_kernel<<<dim3(2048), dim3(256), 0, stream>>>(cur, oth);
    out_init<<<dim3(96), dim3(256), 0, stream>>>(lout_b, out);
    gemm_kernel<<<dim3(768), dim3(256), 0, stream>>>(oth, lout_w, out);
}

// Round 3
// 604.700 us; speedup vs baseline: 1.6314x; 1.4228x over previous
//
#include <hip/hip_runtime.h>
#include <hip/hip_bf16.h>

// Problem constants
#define BB 32   // batch
#define TT 32   // window
#define NN 64   // num_series
#define CC 64   // inter_dim
#define HH 64   // gru hidden
#define QKD 32  // qk dim
#define HOR 12
#define OUTD (NN*HOR)        // 768
#define KFLAT (NN*CC*TT)     // 131072

typedef __attribute__((ext_vector_type(4))) float f32x4;
typedef __attribute__((ext_vector_type(8))) short s16x8;

// round-to-nearest-even fp32 -> bf16 (bit trick)
static __device__ __forceinline__ unsigned short f2bf(float f) {
    unsigned u = __float_as_uint(f);
    unsigned r = (u + 0x7FFFu + ((u >> 16) & 1u)) >> 16;
    return (unsigned short)r;
}

// ---------------- GRU: one wave (64 lanes) per series, 4 series/block -------
__global__ __launch_bounds__(256) void gru_kernel(
    const float* __restrict__ x, const float* __restrict__ wih,
    const float* __restrict__ whh, const float* __restrict__ bih,
    const float* __restrict__ bhh, float* __restrict__ hT)
{
    __shared__ float Wt[64][192];   // Wt[k][g] = whh[g][k]  (48 KB)
    __shared__ float hbuf[4][64];
    int tid = threadIdx.x;
    for (int idx = tid; idx < 192*64; idx += 256) {
        int g = idx >> 6, k = idx & 63;
        Wt[k][g] = whh[idx];
    }
    int ls = tid >> 6;            // local series 0..3 (one wave each)
    int j  = tid & 63;            // hidden index
    int gs = blockIdx.x * 4 + ls; // global series = b*NN + n
    int b = gs >> 6, n = gs & 63;
    hbuf[ls][j] = 0.0f;
    __syncthreads();
    float wih_r = wih[j], wih_z = wih[64+j], wih_n = wih[128+j];
    float bi_r = bih[j], bi_z = bih[64+j], bi_n = bih[128+j];
    float bh_r = bhh[j], bh_z = bhh[64+j], bh_n = bhh[128+j];
    for (int t = 0; t < TT; ++t) {
        float xt = x[(b*TT + t)*NN + n];
        float gr = bh_r, gz = bh_z, gn = bh_n;
        #pragma unroll 8
        for (int k = 0; k < 64; ++k) {
            float hk = hbuf[ls][k];
            gr += hk * Wt[k][j];
            gz += hk * Wt[k][64+j];
            gn += hk * Wt[k][128+j];
        }
        float gir = xt*wih_r + bi_r;
        float giz = xt*wih_z + bi_z;
        float gin = xt*wih_n + bi_n;
        float r = 1.f/(1.f+__expf(-(gir+gr)));
        float z = 1.f/(1.f+__expf(-(giz+gz)));
        float nn = tanhf(gin + r*gn);
        float hnew = (1.f - z)*nn + z*hbuf[ls][j];
        __syncthreads();
        hbuf[ls][j] = hnew;
        __syncthreads();
    }
    hT[gs*64 + j] = hbuf[ls][j];
}

// ---------------- attention -> normalized adjacency What (per batch) --------
__global__ __launch_bounds__(256) void attn_kernel(
    const float* __restrict__ hT, const float* __restrict__ wq_w,
    const float* __restrict__ wq_b, const float* __restrict__ wk_w,
    const float* __restrict__ wk_b, float* __restrict__ What)
{
    __shared__ float hs[64][64];
    __shared__ float Qs[64][32], Ks[64][32];
    __shared__ float S[64][64];
    __shared__ float dinv[64];
    int b = blockIdx.x, tid = threadIdx.x;
    for (int idx = tid; idx < 64*64; idx += 256) hs[idx>>6][idx&63] = hT[b*4096 + idx];
    __syncthreads();
    for (int idx = tid; idx < 64*32; idx += 256) {
        int n_ = idx >> 5, q = idx & 31;
        float accq = wq_b[q], acck = wk_b[q];
        #pragma unroll 8
        for (int h_ = 0; h_ < 64; ++h_) {
            float hv = hs[n_][h_];
            accq += hv * wq_w[q*64 + h_];
            acck += hv * wk_w[q*64 + h_];
        }
        Qs[n_][q] = accq; Ks[n_][q] = acck;
    }
    __syncthreads();
    const float scale = 0.17677669529663687f; // 1/sqrt(32)
    for (int idx = tid; idx < 64*64; idx += 256) {
        int n_ = idx >> 6, m = idx & 63;
        float acc = 0.f;
        #pragma unroll 8
        for (int q = 0; q < 32; ++q) acc += Qs[n_][q]*Ks[m][q];
        S[n_][m] = acc * scale;
    }
    __syncthreads();
    if (tid < 64) {  // row softmax
        float mx = -1e30f;
        for (int m = 0; m < 64; ++m) mx = fmaxf(mx, S[tid][m]);
        float sum = 0.f;
        for (int m = 0; m < 64; ++m) { float e = __expf(S[tid][m]-mx); S[tid][m] = e; sum += e; }
        float inv = 1.f/sum;
        for (int m = 0; m < 64; ++m) S[tid][m] *= inv;
    }
    __syncthreads();
    if (tid < 64) {  // column degree
        float d = 0.f;
        for (int n_ = 0; n_ < 64; ++n_) d += S[n_][tid];
        dinv[tid] = (d > 0.f) ? 1.0f/sqrtf(d) : 0.f;
    }
    __syncthreads();
    for (int idx = tid; idx < 64*64; idx += 256) {
        int n_ = idx >> 6, m = idx & 63;
        What[b*4096 + idx] = dinv[n_]*S[n_][m]*dinv[m];
    }
}

// ---------------- feats init: x_to_inter_dim (1x1 conv) --------------------
__global__ void feats_init(const float* __restrict__ x, const float* __restrict__ w,
                           const float* __restrict__ bb, float* __restrict__ f)
{
    int idx = blockIdx.x*256 + threadIdx.x;   // T*B*N*C = 4194304
    int c = idx & 63;
    int tbn = idx >> 6;
    int n = tbn & 63;
    int tb = tbn >> 6;
    int b = tb & 31;
    int t = tb >> 5;
    f[idx] = x[(b*TT + t)*NN + n] * w[c] + bb[c];
}

// ---------------- fused GCN theta matmul + graph aggregation per (t,b) -----
__global__ __launch_bounds__(256) void gcn_kernel(const float* __restrict__ f,
    const float* __restrict__ gw, const float* __restrict__ What,
    const float* __restrict__ gb, float* __restrict__ o)
{
    __shared__ __align__(16) float ft[64][64];
    __shared__ __align__(16) float wt[64][64];
    __shared__ float xs[64][64];
    int tb = blockIdx.x, t = tb >> 5, b = tb & 31;
    int tid = threadIdx.x, d = tid & 63, ty = tid >> 6;
    const float* fin = f + (size_t)tb*4096;
    const float* wb  = What + (size_t)b*4096;
    for (int idx = tid; idx < 4096; idx += 256) {
        ft[idx>>6][idx&63] = fin[idx];
        wt[idx>>6][idx&63] = wb[idx];
    }
    float g[64];
    const float* gwt = gw + (size_t)t*4096;
    #pragma unroll
    for (int c = 0; c < 64; ++c) g[c] = gwt[c*64 + d];
    __syncthreads();
    {   // xw phase: rows n = ty*16 .. ty*16+15
        float acc[16];
        #pragma unroll
        for (int i = 0; i < 16; ++i) acc[i] = 0.f;
        #pragma unroll
        for (int c4 = 0; c4 < 16; ++c4) {
            #pragma unroll
            for (int i = 0; i < 16; ++i) {
                const float4 fv = *(const float4*)&ft[ty*16 + i][c4*4];
                acc[i] += fv.x*g[4*c4] + fv.y*g[4*c4+1] + fv.z*g[4*c4+2] + fv.w*g[4*c4+3];
            }
        }
        #pragma unroll
        for (int i = 0; i < 16; ++i) xs[ty*16 + i][d] = acc[i];
    }
    __syncthreads();
    {   // agg phase: cols j = ty*16 .. ty*16+15
        float acc[16];
        float bias = gb[t*64 + d];
        #pragma unroll
        for (int i = 0; i < 16; ++i) acc[i] = bias;
        for (int i2 = 0; i2 < 64; ++i2) {
            float xv = xs[i2][d];
            #pragma unroll
            for (int jj = 0; jj < 4; ++jj) {
                const float4 wv = *(const float4*)&wt[i2][ty*16 + jj*4];
                acc[jj*4+0] += wv.x*xv; acc[jj*4+1] += wv.y*xv;
                acc[jj*4+2] += wv.z*xv; acc[jj*4+3] += wv.w*xv;
            }
        }
        float* oo = o + (size_t)tb*4096;
        #pragma unroll
        for (int i = 0; i < 16; ++i) oo[(ty*16 + i)*64 + d] = acc[i];
    }
}

// ---------------- temporal conv1d + LeakyReLU (in-place per (b,n)) ---------
template<int KW>
__global__ __launch_bounds__(256) void conv_kernel(float* __restrict__ g,
                                                   const float* __restrict__ cw,
                                                   const float* __restrict__ cb)
{
    constexpr int P = KW/2;
    __shared__ float seq[32][64];         // [t][ci]
    __shared__ float wls[16*KW][65];      // [ci_l*KW+ka][co], padded stride
    int bn = blockIdx.x;                  // b*NN + n
    int tid = threadIdx.x;
    for (int idx = tid; idx < 32*64; idx += 256) {
        int t = idx >> 6, ci = idx & 63;
        seq[t][ci] = g[((size_t)(t*2048) + bn)*64 + ci];
    }
    int co = tid & 63, tg = tid >> 6;     // tg -> 8 consecutive t's
    float acc[8];
    #pragma unroll
    for (int i = 0; i < 8; ++i) acc[i] = cb[co];
    for (int cc = 0; cc < 4; ++cc) {
        __syncthreads();
        // coalesced weight stage: source runs contiguous per co over (ci_l,ka)
        for (int s = tid; s < 64*16*KW; s += 256) {
            int co_ = s / (16*KW);
            int rem = s - co_*(16*KW);    // ci_l*KW + ka
            wls[rem][co_] = cw[(size_t)(co_*64 + cc*16)*KW + rem];
        }
        __syncthreads();
        for (int ci_l = 0; ci_l < 16; ++ci_l) {
            int ci = cc*16 + ci_l;
            float rv[8 + 2*P];
            #pragma unroll
            for (int u = 0; u < 8 + 2*P; ++u) {
                int ts = tg*8 + u - P;
                rv[u] = (ts >= 0 && ts < 32) ? seq[ts][ci] : 0.f;
            }
            #pragma unroll
            for (int ka = 0; ka < KW; ++ka) {
                float w = wls[ci_l*KW + ka][co];
                #pragma unroll
                for (int tt = 0; tt < 8; ++tt) acc[tt] += rv[tt + ka] * w;
            }
        }
    }
    __syncthreads();
    #pragma unroll
    for (int tt = 0; tt < 8; ++tt) {
        int t = tg*8 + tt;
        float v = acc[tt];
        v = (v >= 0.f) ? v : 0.01f*v;
        g[((size_t)(t*2048) + bn)*64 + co] = v;
    }
}

// ---------------- transpose feats (T,B,N,C) -> bf16 flat (B, n*C*T+c*T+t) --
__global__ void transpose_kernel(const float* __restrict__ f, unsigned short* __restrict__ o)
{
    __shared__ float tl[32][65];
    int bn = blockIdx.x;                  // b*NN + n
    int tid = threadIdx.x;
    for (int idx = tid; idx < 2048; idx += 256) {
        int t = idx >> 6, c = idx & 63;
        tl[t][c] = f[((size_t)t*2048 + bn)*64 + c];
    }
    __syncthreads();
    int b = bn >> 6, n = bn & 63;
    unsigned short* ob = o + (size_t)b*KFLAT + n*2048;
    for (int idx = tid; idx < 2048; idx += 256) {
        int c = idx >> 5, t = idx & 31;
        ob[c*32 + t] = f2bf(tl[t][c]);
    }
}

// ---------------- output init with bias ------------------------------------
__global__ void out_init(const float* __restrict__ bias, float* __restrict__ out)
{
    int idx = blockIdx.x*256 + threadIdx.x;   // 24576
    out[idx] = bias[idx % OUTD];
}

// ---------------- final GEMM via MFMA, bf16 hi/lo split of W ----------------
// out[b][o] += sum_k flat[b][k] * W[o][k].  Grid: 12 o-groups x 64 k-chunks.
// Per block: 64 o x 32 b x 2048 k. LDS double-buffered tiles:
//   Wl: 64o x 64k fp32 (16 KB), Al: 32b x 64k bf16 (4 KB); XOR unit-swizzle
//   applied at the GLOBAL source so LDS stays write-linear, reads conflict-free.
// W is split hi/lo bf16 in-register -> 2 MFMAs, ~16 mantissa bits of W kept.
__global__ __launch_bounds__(256) void gemm_mfma(const unsigned short* __restrict__ flat,
                                                 const float* __restrict__ W,
                                                 float* __restrict__ out)
{
    __shared__ __align__(16) float Wl[2][64][64];            // 32 KB
    __shared__ __align__(16) unsigned short Al[2][32][64];   // 8 KB
    const int tid = threadIdx.x;
    const int w = tid >> 6, l = tid & 63;
    const int og = blockIdx.x >> 6;        // 0..11
    const int kc = blockIdx.x & 63;        // 0..63
    const int o_blk = og * 64;
    const int kbase = kc * 2048;

    // staging maps
    const int sb = tid >> 3, su = tid & 7;                 // A: row sb, 16B unit su
    const size_t a_src = (size_t)sb * KFLAT + (unsigned)((su ^ (sb & 7)) * 8);

    float4 tw0, tw1, tw2, tw3; uint4 ta;

#define ISSUE(s_) { \
    int kwin_ = kbase + (s_)*64; \
    { int g_ = 0*256 + tid; int o_ = g_ >> 4; int u_ = g_ & 15; \
      tw0 = *(const float4*)&W[(size_t)(o_blk + o_)*KFLAT + kwin_ + ((u_ ^ (o_ & 7))*4)]; } \
    { int g_ = 1*256 + tid; int o_ = g_ >> 4; int u_ = g_ & 15; \
      tw1 = *(const float4*)&W[(size_t)(o_blk + o_)*KFLAT + kwin_ + ((u_ ^ (o_ & 7))*4)]; } \
    { int g_ = 2*256 + tid; int o_ = g_ >> 4; int u_ = g_ & 15; \
      tw2 = *(const float4*)&W[(size_t)(o_blk + o_)*KFLAT + kwin_ + ((u_ ^ (o_ & 7))*4)]; } \
    { int g_ = 3*256 + tid; int o_ = g_ >> 4; int u_ = g_ & 15; \
      tw3 = *(const float4*)&W[(size_t)(o_blk + o_)*KFLAT + kwin_ + ((u_ ^ (o_ & 7))*4)]; } \
    ta = *(const uint4*)&flat[a_src + kwin_]; }

#define COMMIT(nb_) { \
    { int g_ = 0*256 + tid; *(float4*)&Wl[nb_][g_>>4][(g_&15)*4] = tw0; } \
    { int g_ = 1*256 + tid; *(float4*)&Wl[nb_][g_>>4][(g_&15)*4] = tw1; } \
    { int g_ = 2*256 + tid; *(float4*)&Wl[nb_][g_>>4][(g_&15)*4] = tw2; } \
    { int g_ = 3*256 + tid; *(float4*)&Wl[nb_][g_>>4][(g_&15)*4] = tw3; } \
    *(uint4*)&Al[nb_][sb][su*8] = ta; }

    f32x4 acc0 = {0.f,0.f,0.f,0.f}, acc1 = {0.f,0.f,0.f,0.f};

    ISSUE(0);
    COMMIT(0);
    ISSUE(1);
    __syncthreads();

    const int lmod = l & 15, ldiv = l >> 4, lx = l & 7;
    int cur = 0;
    for (int s = 0; s < 32; ++s) {
        #pragma unroll
        for (int ksub = 0; ksub < 2; ++ksub) {
            // B fragment: 8 consecutive fp32 of W[o][k], swizzled units
            int ju = ksub*8 + ldiv*2;
            const float4 b0 = *(const float4*)&Wl[cur][w*16 + lmod][(ju ^ lx)*4];
            const float4 b1 = *(const float4*)&Wl[cur][w*16 + lmod][((ju+1) ^ lx)*4];
            float bf[8] = {b0.x,b0.y,b0.z,b0.w,b1.x,b1.y,b1.z,b1.w};
            s16x8 bhi, blo;
            #pragma unroll
            for (int i = 0; i < 8; ++i) {
                unsigned short h = f2bf(bf[i]);
                float hf = __uint_as_float(((unsigned)h) << 16);
                bhi[i] = (short)h;
                blo[i] = (short)f2bf(bf[i] - hf);
            }
            int jua = ksub*4 + ldiv;
            const s16x8 a0 = *(const s16x8*)&Al[cur][lmod]      [(jua ^ lx)*8];
            const s16x8 a1 = *(const s16x8*)&Al[cur][16 + lmod] [(jua ^ lx)*8];
            acc0 = __builtin_amdgcn_mfma_f32_16x16x32_bf16(a0, bhi, acc0, 0, 0, 0);
            acc0 = __builtin_amdgcn_mfma_f32_16x16x32_bf16(a0, blo, acc0, 0, 0, 0);
            acc1 = __builtin_amdgcn_mfma_f32_16x16x32_bf16(a1, bhi, acc1, 0, 0, 0);
            acc1 = __builtin_amdgcn_mfma_f32_16x16x32_bf16(a1, blo, acc1, 0, 0, 0);
        }
        if (s < 31) {
            COMMIT(cur^1);
            if (s < 30) ISSUE(s+2);
        }
        __syncthreads();
        cur ^= 1;
    }
#undef ISSUE
#undef COMMIT

    // epilogue: D row=(l>>4)*4+r (batch within tile), col=l&15 (o within wave)
    const int o_out = o_blk + w*16 + lmod;
    #pragma unroll
    for (int r = 0; r < 4; ++r) {
        int b0_ = ldiv*4 + r;
        atomicAdd(&out[(size_t)b0_*OUTD + o_out], acc0[r]);
        atomicAdd(&out[(size_t)(16 + b0_)*OUTD + o_out], acc1[r]);
    }
}

extern "C" void kernel_launch(void* const* d_in, const int* in_sizes, int n_in,
                              void* d_out, int out_size, void* d_ws, size_t ws_size,
                              hipStream_t stream) {
    (void)in_sizes; (void)n_in; (void)out_size; (void)ws_size;
    const float* x        = (const float*)d_in[0];
    const float* w_x2i    = (const float*)d_in[1];
    const float* b_x2i    = (const float*)d_in[2];
    const float* gru_wih  = (const float*)d_in[3];
    const float* gru_whh  = (const float*)d_in[4];
    const float* gru_bih  = (const float*)d_in[5];
    const float* gru_bhh  = (const float*)d_in[6];
    const float* wq_w     = (const float*)d_in[7];
    const float* wq_b     = (const float*)d_in[8];
    const float* wk_w     = (const float*)d_in[9];
    const float* wk_b     = (const float*)d_in[10];
    const float* gcn_w[3]  = {(const float*)d_in[11], (const float*)d_in[15], (const float*)d_in[19]};
    const float* gcn_b[3]  = {(const float*)d_in[12], (const float*)d_in[16], (const float*)d_in[20]};
    const float* conv_w[3] = {(const float*)d_in[13], (const float*)d_in[17], (const float*)d_in[21]};
    const float* conv_b[3] = {(const float*)d_in[14], (const float*)d_in[18], (const float*)d_in[22]};
    const float* lout_w   = (const float*)d_in[23];
    const float* lout_b   = (const float*)d_in[24];
    float* out = (float*)d_out;
    float* ws  = (float*)d_ws;

    float* hT   = ws;                    // 131072
    float* What = ws + 131072;           // 131072
    float* bufA = ws + 262144;           // 4194304 floats
    float* bufB = bufA + 4194304;        // 4194304 floats

    gru_kernel<<<dim3(512), dim3(256), 0, stream>>>(x, gru_wih, gru_whh, gru_bih, gru_bhh, hT);
    attn_kernel<<<dim3(32), dim3(256), 0, stream>>>(hT, wq_w, wq_b, wk_w, wk_b, What);
    feats_init<<<dim3(16384), dim3(256), 0, stream>>>(x, w_x2i, b_x2i, bufA);

    float* cur = bufA; float* oth = bufB;
    for (int i = 0; i < 3; ++i) {
        gcn_kernel<<<dim3(1024), dim3(256), 0, stream>>>(cur, gcn_w[i], What, gcn_b[i], oth);
        if (i == 0) conv_kernel<3><<<dim3(2048), dim3(256), 0, stream>>>(oth, conv_w[i], conv_b[i]);
        if (i == 1) conv_kernel<5><<<dim3(2048), dim3(256), 0, stream>>>(oth, conv_w[i], conv_b[i]);
        if (i == 2) conv_kernel<7><<<dim3(2048), dim3(256), 0, stream>>>(oth, conv_w[i], conv_b[i]);
        float* tmp = cur; cur = oth; oth = tmp;
    }
    // bf16 flat written into the free ping-pong buffer (reused as ushort)
    unsigned short* flat16 = (unsigned short*)oth;
    transpose_kernel<<<dim3(2048), dim3(256), 0, stream>>>(cur, flat16);
    out_init<<<dim3(96), dim3(256), 0, stream>>>(lout_b, out);
    gemm_mfma<<<dim3(768), dim3(256), 0, stream>>>(flat16, lout_w, out);
}

// Round 4
// 344.887 us; speedup vs baseline: 2.8604x; 1.7533x over previous
//
#include <hip/hip_runtime.h>
#include <hip/hip_bf16.h>

// Problem constants
#define BB 32   // batch
#define TT 32   // window
#define NN 64   // num_series
#define CC 64   // inter_dim
#define HH 64   // gru hidden
#define QKD 32  // qk dim
#define HOR 12
#define OUTD (NN*HOR)        // 768
#define KFLAT (NN*CC*TT)     // 131072

typedef __attribute__((ext_vector_type(4))) float f32x4;
typedef __attribute__((ext_vector_type(8))) short s16x8;

// round-to-nearest-even fp32 -> bf16 (bit trick)
static __device__ __forceinline__ unsigned short f2bf(float f) {
    unsigned u = __float_as_uint(f);
    unsigned r = (u + 0x7FFFu + ((u >> 16) & 1u)) >> 16;
    return (unsigned short)r;
}
static __device__ __forceinline__ float bf2f(unsigned short h) {
    return __uint_as_float(((unsigned)h) << 16);
}
// split 8 fp32 -> 8 bf16 hi + 8 bf16 lo, packed as uint4 each
static __device__ __forceinline__ void split8(const float* f, uint4& hi, uint4& lo) {
    unsigned hh[8], ll[8];
    #pragma unroll
    for (int i = 0; i < 8; ++i) {
        unsigned short h = f2bf(f[i]);
        float hf = bf2f(h);
        hh[i] = h;
        ll[i] = f2bf(f[i] - hf);
    }
    hi = make_uint4(hh[0] | (hh[1] << 16), hh[2] | (hh[3] << 16),
                    hh[4] | (hh[5] << 16), hh[6] | (hh[7] << 16));
    lo = make_uint4(ll[0] | (ll[1] << 16), ll[2] | (ll[3] << 16),
                    ll[4] | (ll[5] << 16), ll[6] | (ll[7] << 16));
}

// ---------------- GRU: wave-specialized k-chunks, Whh in registers ---------
__global__ __launch_bounds__(256) void gru_kernel(
    const float* __restrict__ x, const float* __restrict__ wih,
    const float* __restrict__ whh, const float* __restrict__ bih,
    const float* __restrict__ bhh, float* __restrict__ hT)
{
    __shared__ float Wt[64][192];          // Wt[k][G] = whh[G][k]
    __shared__ float hbuf[4][64];
    __shared__ float part[4][4][3][64];    // [kchunk-wave][series][gate][j]
    int tid = threadIdx.x;
    for (int idx = tid; idx < 192*64; idx += 256) {
        int g = idx >> 6, k = idx & 63;
        Wt[k][g] = whh[idx];
    }
    int w = tid >> 6;            // wave id: k-chunk owner AND series owner
    int j = tid & 63;
    hbuf[w][j] = 0.0f;
    __syncthreads();
    float Wreg[3][16];
    #pragma unroll
    for (int g = 0; g < 3; ++g)
        #pragma unroll
        for (int kk = 0; kk < 16; ++kk)
            Wreg[g][kk] = Wt[w*16 + kk][g*64 + j];
    int gs0 = blockIdx.x * 4;
    int b = gs0 >> 6, n0 = gs0 & 63;
    float wih_r = wih[j], wih_z = wih[64+j], wih_n = wih[128+j];
    float bi_r = bih[j], bi_z = bih[64+j], bi_n = bih[128+j];
    float bh_r = bhh[j], bh_z = bhh[64+j], bh_n = bhh[128+j];
    float hreg = 0.0f;
    for (int t = 0; t < TT; ++t) {
        float p[3][4];
        #pragma unroll
        for (int g = 0; g < 3; ++g)
            #pragma unroll
            for (int s = 0; s < 4; ++s) p[g][s] = 0.f;
        #pragma unroll
        for (int s = 0; s < 4; ++s) {
            #pragma unroll
            for (int q = 0; q < 4; ++q) {
                const float4 hv = *(const float4*)&hbuf[s][w*16 + q*4];
                #pragma unroll
                for (int g = 0; g < 3; ++g) {
                    p[g][s] += hv.x*Wreg[g][q*4]   + hv.y*Wreg[g][q*4+1]
                             + hv.z*Wreg[g][q*4+2] + hv.w*Wreg[g][q*4+3];
                }
            }
        }
        #pragma unroll
        for (int g = 0; g < 3; ++g)
            #pragma unroll
            for (int s = 0; s < 4; ++s)
                part[w][s][g][j] = p[g][s];
        __syncthreads();
        float gr = bh_r + part[0][w][0][j] + part[1][w][0][j] + part[2][w][0][j] + part[3][w][0][j];
        float gz = bh_z + part[0][w][1][j] + part[1][w][1][j] + part[2][w][1][j] + part[3][w][1][j];
        float gn = bh_n + part[0][w][2][j] + part[1][w][2][j] + part[2][w][2][j] + part[3][w][2][j];
        float xt = x[(b*TT + t)*NN + n0 + w];
        float r = 1.f/(1.f+__expf(-(xt*wih_r + bi_r + gr)));
        float z = 1.f/(1.f+__expf(-(xt*wih_z + bi_z + gz)));
        float nn_ = tanhf(xt*wih_n + bi_n + r*gn);
        float hnew = (1.f - z)*nn_ + z*hreg;
        hreg = hnew;
        hbuf[w][j] = hnew;
        __syncthreads();
    }
    hT[(gs0 + w)*64 + j] = hreg;
}

// ---------------- attention -> WhatT hi/lo bf16 (per batch) ----------------
__global__ __launch_bounds__(256) void attn_kernel(
    const float* __restrict__ hT, const float* __restrict__ wq_w,
    const float* __restrict__ wq_b, const float* __restrict__ wk_w,
    const float* __restrict__ wk_b,
    unsigned short* __restrict__ whT_hi, unsigned short* __restrict__ whT_lo)
{
    __shared__ float hs[64][64];
    __shared__ float Qs[64][32], Ks[64][32];
    __shared__ float S[64][64];
    __shared__ float dinv[64];
    int b = blockIdx.x, tid = threadIdx.x;
    for (int idx = tid; idx < 64*64; idx += 256) hs[idx>>6][idx&63] = hT[b*4096 + idx];
    __syncthreads();
    for (int idx = tid; idx < 64*32; idx += 256) {
        int n_ = idx >> 5, q = idx & 31;
        float accq = wq_b[q], acck = wk_b[q];
        #pragma unroll 8
        for (int h_ = 0; h_ < 64; ++h_) {
            float hv = hs[n_][h_];
            accq += hv * wq_w[q*64 + h_];
            acck += hv * wk_w[q*64 + h_];
        }
        Qs[n_][q] = accq; Ks[n_][q] = acck;
    }
    __syncthreads();
    const float scale = 0.17677669529663687f; // 1/sqrt(32)
    for (int idx = tid; idx < 64*64; idx += 256) {
        int n_ = idx >> 6, m = idx & 63;
        float acc = 0.f;
        #pragma unroll 8
        for (int q = 0; q < 32; ++q) acc += Qs[n_][q]*Ks[m][q];
        S[n_][m] = acc * scale;
    }
    __syncthreads();
    if (tid < 64) {  // row softmax
        float mx = -1e30f;
        for (int m = 0; m < 64; ++m) mx = fmaxf(mx, S[tid][m]);
        float sum = 0.f;
        for (int m = 0; m < 64; ++m) { float e = __expf(S[tid][m]-mx); S[tid][m] = e; sum += e; }
        float inv = 1.f/sum;
        for (int m = 0; m < 64; ++m) S[tid][m] *= inv;
    }
    __syncthreads();
    if (tid < 64) {  // column degree
        float d = 0.f;
        for (int n_ = 0; n_ < 64; ++n_) d += S[n_][tid];
        dinv[tid] = (d > 0.f) ? 1.0f/sqrtf(d) : 0.f;
    }
    __syncthreads();
    // WhatT[j][i] = dinv[i]*S[i][j]*dinv[j], split hi/lo
    for (int idx = tid; idx < 64*64; idx += 256) {
        int jj = idx >> 6, ii = idx & 63;
        float val = dinv[ii]*S[ii][jj]*dinv[jj];
        unsigned short h = f2bf(val);
        whT_hi[b*4096 + idx] = h;
        whT_lo[b*4096 + idx] = f2bf(val - bf2f(h));
    }
}

// ---------------- prep: u/v for rank-1 first GCN ---------------------------
__global__ __launch_bounds__(256) void prep_uv(const float* __restrict__ gw0,
    const float* __restrict__ wx, const float* __restrict__ bx,
    float* __restrict__ u, float* __restrict__ v)
{
    __shared__ float pu[4][64], pv[4][64];
    int t = blockIdx.x, tid = threadIdx.x, d = tid & 63, cq = tid >> 6;
    float su = 0.f, sv = 0.f;
    for (int c = cq*16; c < cq*16 + 16; ++c) {
        float gv = gw0[t*4096 + c*64 + d];
        su += wx[c]*gv; sv += bx[c]*gv;
    }
    pu[cq][d] = su; pv[cq][d] = sv;
    __syncthreads();
    if (tid < 64) {
        u[t*64 + tid] = pu[0][tid]+pu[1][tid]+pu[2][tid]+pu[3][tid];
        v[t*64 + tid] = pv[0][tid]+pv[1][tid]+pv[2][tid]+pv[3][tid];
    }
}

// ---------------- prep: gw -> transposed hi/lo bf16 [t][d][c] --------------
__global__ __launch_bounds__(256) void prep_gwT(const float* __restrict__ gw,
    unsigned short* __restrict__ hi, unsigned short* __restrict__ lo)
{
    int t = blockIdx.x, tid = threadIdx.x;
    for (int idx = tid; idx < 4096; idx += 256) {
        int d = idx >> 6, c = idx & 63;
        float val = gw[t*4096 + c*64 + d];
        unsigned short h = f2bf(val);
        hi[t*4096 + idx] = h;
        lo[t*4096 + idx] = f2bf(val - bf2f(h));
    }
}

// ---------------- prep: conv w -> [co][ka*64+ci] hi/lo bf16 ----------------
__global__ __launch_bounds__(256) void prep_cw(const float* __restrict__ cw,
    unsigned short* __restrict__ hi, unsigned short* __restrict__ lo, int KW)
{
    int co = blockIdx.x, tid = threadIdx.x, K = KW*64;
    for (int idx = tid; idx < K; idx += 256) {
        int ka = idx >> 6, ci = idx & 63;
        float val = cw[(size_t)(co*64 + ci)*KW + ka];
        unsigned short h = f2bf(val);
        hi[(size_t)co*K + idx] = h;
        lo[(size_t)co*K + idx] = f2bf(val - bf2f(h));
    }
}

// ---------------- GCN via MFMA (hi/lo split, fp32-class precision) ---------
// mm1: xs[n][d] = sum_c ft[n][c]*gw[t][c][d]  (FIRST: ft rank-1 -> x*u+v)
// mm2: out[j][d] = gb[t][d] + sum_i WhatT[j][i]*xs[i][d]
template<bool FIRST>
__global__ __launch_bounds__(256) void gcn_mfma(
    const float* __restrict__ fin,         // !FIRST: feats [t][b][n][c]; FIRST: x (B,T,N)
    const unsigned short* __restrict__ gwT_hi, const unsigned short* __restrict__ gwT_lo,
    const float* __restrict__ u, const float* __restrict__ v,
    const unsigned short* __restrict__ whT_hi, const unsigned short* __restrict__ whT_lo,
    const float* __restrict__ gb, float* __restrict__ o)
{
    __shared__ __align__(16) unsigned short ft_hi[64][64], ft_lo[64][64];   // 16 KB
    __shared__ __align__(16) unsigned short xsT_hi[64][64], xsT_lo[64][64]; // 16 KB
    __shared__ float x_l[64];
    int tb = blockIdx.x, t = tb >> 5, b = tb & 31;
    int tid = threadIdx.x;
    int w = tid >> 6, l = tid & 63, lm = l & 15, ld = l >> 4;

    if (FIRST) {
        if (tid < 64) x_l[tid] = fin[(b*TT + t)*NN + tid];
        __syncthreads();
        // xs[n][d] = x[n]*u[t][d] + v[t][d]; write transposed split
        int d = tid >> 2, nq = tid & 3;          // n0 = nq*16
        float ud = u[t*64 + d], vd = v[t*64 + d];
        float vals[16];
        #pragma unroll
        for (int i = 0; i < 16; ++i) vals[i] = x_l[nq*16 + i]*ud + vd;
        #pragma unroll
        for (int h = 0; h < 2; ++h) {
            uint4 hi, lo; split8(&vals[h*8], hi, lo);
            int un = (nq*2 + h) ^ (d & 7);
            *(uint4*)&xsT_hi[d][un*8] = hi;
            *(uint4*)&xsT_lo[d][un*8] = lo;
        }
        __syncthreads();
    } else {
        // stage ft split (row n, cols c), unit-swizzled
        {
            int row = tid >> 2, c0 = (tid & 3) * 16;
            const float* src = fin + (size_t)tb*4096 + row*64 + c0;
            float f8a[8], f8b[8];
            *(float4*)f8a = *(const float4*)src;       *(float4*)(f8a+4) = *(const float4*)(src+4);
            *(float4*)f8b = *(const float4*)(src+8);   *(float4*)(f8b+4) = *(const float4*)(src+12);
            uint4 hi, lo;
            split8(f8a, hi, lo);
            int u0 = ((c0>>3)) ^ (row & 7);
            *(uint4*)&ft_hi[row][u0*8] = hi; *(uint4*)&ft_lo[row][u0*8] = lo;
            split8(f8b, hi, lo);
            int u1 = ((c0>>3)+1) ^ (row & 7);
            *(uint4*)&ft_hi[row][u1*8] = hi; *(uint4*)&ft_lo[row][u1*8] = lo;
        }
        __syncthreads();
        // mm1: wave = M-tile (rows n), acc over 4 N-tiles (d)
        f32x4 acc[4];
        #pragma unroll
        for (int ct = 0; ct < 4; ++ct) acc[ct] = (f32x4){0.f,0.f,0.f,0.f};
        #pragma unroll
        for (int kc = 0; kc < 2; ++kc) {
            int nrow = w*16 + lm;
            int ux = (kc*4 + ld) ^ (nrow & 7);
            s16x8 xh = *(const s16x8*)&ft_hi[nrow][ux*8];
            s16x8 xl = *(const s16x8*)&ft_lo[nrow][ux*8];
            #pragma unroll
            for (int ct = 0; ct < 4; ++ct) {
                int drow = ct*16 + lm;
                s16x8 yh = *(const s16x8*)&gwT_hi[t*4096 + drow*64 + kc*32 + ld*8];
                s16x8 yl = *(const s16x8*)&gwT_lo[t*4096 + drow*64 + kc*32 + ld*8];
                acc[ct] = __builtin_amdgcn_mfma_f32_16x16x32_bf16(xh, yh, acc[ct], 0, 0, 0);
                acc[ct] = __builtin_amdgcn_mfma_f32_16x16x32_bf16(xh, yl, acc[ct], 0, 0, 0);
                acc[ct] = __builtin_amdgcn_mfma_f32_16x16x32_bf16(xl, yh, acc[ct], 0, 0, 0);
            }
        }
        // write xsT[d][n] split: 4 consecutive n per lane -> b64 hi + b64 lo
        #pragma unroll
        for (int ct = 0; ct < 4; ++ct) {
            int d = ct*16 + lm;
            int n0 = w*16 + ld*4;
            unsigned short hh[4], llo[4];
            #pragma unroll
            for (int r = 0; r < 4; ++r) {
                float val = acc[ct][r];
                unsigned short h = f2bf(val);
                hh[r] = h; llo[r] = f2bf(val - bf2f(h));
            }
            int un = (n0 >> 3) ^ (d & 7);
            int base = d*64 + un*8 + (n0 & 7);
            *(uint2*)&xsT_hi[0][0 + base] = make_uint2(hh[0]|(hh[1]<<16), hh[2]|(hh[3]<<16));
            *(uint2*)&xsT_lo[0][0 + base] = make_uint2(llo[0]|(llo[1]<<16), llo[2]|(llo[3]<<16));
        }
        __syncthreads();
    }

    // mm2: wave = M-tile (rows j), acc over 4 N-tiles (d)
    f32x4 acc2[4];
    #pragma unroll
    for (int ct = 0; ct < 4; ++ct) acc2[ct] = (f32x4){0.f,0.f,0.f,0.f};
    #pragma unroll
    for (int kc = 0; kc < 2; ++kc) {
        int jrow = w*16 + lm;
        s16x8 wh = *(const s16x8*)&whT_hi[b*4096 + jrow*64 + kc*32 + ld*8];
        s16x8 wl = *(const s16x8*)&whT_lo[b*4096 + jrow*64 + kc*32 + ld*8];
        #pragma unroll
        for (int ct = 0; ct < 4; ++ct) {
            int drow = ct*16 + lm;
            int uy = (kc*4 + ld) ^ (drow & 7);
            s16x8 yh = *(const s16x8*)&xsT_hi[drow][uy*8];
            s16x8 yl = *(const s16x8*)&xsT_lo[drow][uy*8];
            acc2[ct] = __builtin_amdgcn_mfma_f32_16x16x32_bf16(wh, yh, acc2[ct], 0, 0, 0);
            acc2[ct] = __builtin_amdgcn_mfma_f32_16x16x32_bf16(wh, yl, acc2[ct], 0, 0, 0);
            acc2[ct] = __builtin_amdgcn_mfma_f32_16x16x32_bf16(wl, yh, acc2[ct], 0, 0, 0);
        }
    }
    float* oo = o + (size_t)tb*4096;
    #pragma unroll
    for (int ct = 0; ct < 4; ++ct) {
        int d = ct*16 + lm;
        float bias = gb[t*64 + d];
        #pragma unroll
        for (int r = 0; r < 4; ++r) {
            int jj = w*16 + ld*4 + r;
            oo[jj*64 + d] = acc2[ct][r] + bias;
        }
    }
}

// ---------------- temporal conv1d via im2col MFMA + LeakyReLU (in-place) ---
template<int KW>
__global__ __launch_bounds__(256) void conv_mfma(float* __restrict__ g,
    const unsigned short* __restrict__ wch, const unsigned short* __restrict__ wcl,
    const float* __restrict__ cb)
{
    constexpr int P = KW/2, K = KW*64, K32 = KW*2;
    __shared__ __align__(16) unsigned short sh[32][64], sl[32][64];  // 8 KB
    int bn = blockIdx.x, tid = threadIdx.x;
    {
        int t = tid >> 3, c0 = (tid & 7) * 8;
        const float* src = &g[((size_t)t*2048 + bn)*64 + c0];
        float f8[8];
        *(float4*)f8 = *(const float4*)src;
        *(float4*)(f8+4) = *(const float4*)(src+4);
        uint4 hi, lo; split8(f8, hi, lo);
        int uu = (tid & 7) ^ (t & 7);
        *(uint4*)&sh[t][uu*8] = hi;
        *(uint4*)&sl[t][uu*8] = lo;
    }
    __syncthreads();
    int w = tid >> 6, l = tid & 63, lm = l & 15, ld = l >> 4;
    int co = w*16 + lm;
    f32x4 acc0 = {0.f,0.f,0.f,0.f}, acc1 = {0.f,0.f,0.f,0.f};
    const s16x8 zf = {0,0,0,0,0,0,0,0};
    for (int kc = 0; kc < K32; ++kc) {
        int ka = kc >> 1;
        int ci = (kc & 1)*32 + ld*8;
        s16x8 yh = *(const s16x8*)&wch[(size_t)co*K + kc*32 + ld*8];
        s16x8 yl = *(const s16x8*)&wcl[(size_t)co*K + kc*32 + ld*8];
        #pragma unroll
        for (int Mt = 0; Mt < 2; ++Mt) {
            int ts = Mt*16 + lm + ka - P;
            bool ok = ((unsigned)ts) < 32u;
            int tc = ok ? ts : 0;
            int ua = (ci >> 3) ^ (tc & 7);
            s16x8 xh = *(const s16x8*)&sh[tc][ua*8];
            s16x8 xl = *(const s16x8*)&sl[tc][ua*8];
            if (!ok) { xh = zf; xl = zf; }
            f32x4& a = Mt ? acc1 : acc0;
            a = __builtin_amdgcn_mfma_f32_16x16x32_bf16(xh, yh, a, 0, 0, 0);
            a = __builtin_amdgcn_mfma_f32_16x16x32_bf16(xh, yl, a, 0, 0, 0);
            a = __builtin_amdgcn_mfma_f32_16x16x32_bf16(xl, yh, a, 0, 0, 0);
        }
    }
    float bias = cb[co];
    #pragma unroll
    for (int Mt = 0; Mt < 2; ++Mt) {
        const f32x4& a = Mt ? acc1 : acc0;
        #pragma unroll
        for (int r = 0; r < 4; ++r) {
            int t = Mt*16 + ld*4 + r;
            float val = a[r] + bias;
            val = (val >= 0.f) ? val : 0.01f*val;
            g[((size_t)t*2048 + bn)*64 + co] = val;
        }
    }
}

// ---------------- transpose feats (T,B,N,C) -> bf16 flat (B, n*C*T+c*T+t) --
__global__ void transpose_kernel(const float* __restrict__ f, unsigned short* __restrict__ o)
{
    __shared__ float tl[32][65];
    int bn = blockIdx.x;                  // b*NN + n
    int tid = threadIdx.x;
    for (int idx = tid; idx < 2048; idx += 256) {
        int t = idx >> 6, c = idx & 63;
        tl[t][c] = f[((size_t)t*2048 + bn)*64 + c];
    }
    __syncthreads();
    int b = bn >> 6, n = bn & 63;
    unsigned short* ob = o + (size_t)b*KFLAT + n*2048;
    for (int idx = tid; idx < 2048; idx += 256) {
        int c = idx >> 5, t = idx & 31;
        ob[c*32 + t] = f2bf(tl[t][c]);
    }
}

// ---------------- output init with bias ------------------------------------
__global__ void out_init(const float* __restrict__ bias, float* __restrict__ out)
{
    int idx = blockIdx.x*256 + threadIdx.x;   // 24576
    out[idx] = bias[idx % OUTD];
}

// ---------------- final GEMM via MFMA, bf16 hi/lo split of W ----------------
__global__ __launch_bounds__(256) void gemm_mfma(const unsigned short* __restrict__ flat,
                                                 const float* __restrict__ W,
                                                 float* __restrict__ out)
{
    __shared__ __align__(16) float Wl[2][64][64];            // 32 KB
    __shared__ __align__(16) unsigned short Al[2][32][64];   // 8 KB
    const int tid = threadIdx.x;
    const int w = tid >> 6, l = tid & 63;
    const int og = blockIdx.x >> 6;        // 0..11
    const int kc = blockIdx.x & 63;        // 0..63
    const int o_blk = og * 64;
    const int kbase = kc * 2048;

    const int sb = tid >> 3, su = tid & 7;                 // A: row sb, 16B unit su
    const size_t a_src = (size_t)sb * KFLAT + (unsigned)((su ^ (sb & 7)) * 8);

    float4 tw0, tw1, tw2, tw3; uint4 ta;

#define ISSUE(s_) { \
    int kwin_ = kbase + (s_)*64; \
    { int g_ = 0*256 + tid; int o_ = g_ >> 4; int u_ = g_ & 15; \
      tw0 = *(const float4*)&W[(size_t)(o_blk + o_)*KFLAT + kwin_ + ((u_ ^ (o_ & 7))*4)]; } \
    { int g_ = 1*256 + tid; int o_ = g_ >> 4; int u_ = g_ & 15; \
      tw1 = *(const float4*)&W[(size_t)(o_blk + o_)*KFLAT + kwin_ + ((u_ ^ (o_ & 7))*4)]; } \
    { int g_ = 2*256 + tid; int o_ = g_ >> 4; int u_ = g_ & 15; \
      tw2 = *(const float4*)&W[(size_t)(o_blk + o_)*KFLAT + kwin_ + ((u_ ^ (o_ & 7))*4)]; } \
    { int g_ = 3*256 + tid; int o_ = g_ >> 4; int u_ = g_ & 15; \
      tw3 = *(const float4*)&W[(size_t)(o_blk + o_)*KFLAT + kwin_ + ((u_ ^ (o_ & 7))*4)]; } \
    ta = *(const uint4*)&flat[a_src + kwin_]; }

#define COMMIT(nb_) { \
    { int g_ = 0*256 + tid; *(float4*)&Wl[nb_][g_>>4][(g_&15)*4] = tw0; } \
    { int g_ = 1*256 + tid; *(float4*)&Wl[nb_][g_>>4][(g_&15)*4] = tw1; } \
    { int g_ = 2*256 + tid; *(float4*)&Wl[nb_][g_>>4][(g_&15)*4] = tw2; } \
    { int g_ = 3*256 + tid; *(float4*)&Wl[nb_][g_>>4][(g_&15)*4] = tw3; } \
    *(uint4*)&Al[nb_][sb][su*8] = ta; }

    f32x4 acc0 = {0.f,0.f,0.f,0.f}, acc1 = {0.f,0.f,0.f,0.f};

    ISSUE(0);
    COMMIT(0);
    ISSUE(1);
    __syncthreads();

    const int lmod = l & 15, ldiv = l >> 4, lx = l & 7;
    int cur = 0;
    for (int s = 0; s < 32; ++s) {
        #pragma unroll
        for (int ksub = 0; ksub < 2; ++ksub) {
            int ju = ksub*8 + ldiv*2;
            const float4 b0 = *(const float4*)&Wl[cur][w*16 + lmod][(ju ^ lx)*4];
            const float4 b1 = *(const float4*)&Wl[cur][w*16 + lmod][((ju+1) ^ lx)*4];
            float bf[8] = {b0.x,b0.y,b0.z,b0.w,b1.x,b1.y,b1.z,b1.w};
            s16x8 bhi, blo;
            #pragma unroll
            for (int i = 0; i < 8; ++i) {
                unsigned short h = f2bf(bf[i]);
                float hf = bf2f(h);
                bhi[i] = (short)h;
                blo[i] = (short)f2bf(bf[i] - hf);
            }
            int jua = ksub*4 + ldiv;
            const s16x8 a0 = *(const s16x8*)&Al[cur][lmod]      [(jua ^ lx)*8];
            const s16x8 a1 = *(const s16x8*)&Al[cur][16 + lmod] [(jua ^ lx)*8];
            acc0 = __builtin_amdgcn_mfma_f32_16x16x32_bf16(a0, bhi, acc0, 0, 0, 0);
            acc0 = __builtin_amdgcn_mfma_f32_16x16x32_bf16(a0, blo, acc0, 0, 0, 0);
            acc1 = __builtin_amdgcn_mfma_f32_16x16x32_bf16(a1, bhi, acc1, 0, 0, 0);
            acc1 = __builtin_amdgcn_mfma_f32_16x16x32_bf16(a1, blo, acc1, 0, 0, 0);
        }
        if (s < 31) {
            COMMIT(cur^1);
            if (s < 30) ISSUE(s+2);
        }
        __syncthreads();
        cur ^= 1;
    }
#undef ISSUE
#undef COMMIT

    const int o_out = o_blk + w*16 + lmod;
    #pragma unroll
    for (int r = 0; r < 4; ++r) {
        int b0_ = ldiv*4 + r;
        atomicAdd(&out[(size_t)b0_*OUTD + o_out], acc0[r]);
        atomicAdd(&out[(size_t)(16 + b0_)*OUTD + o_out], acc1[r]);
    }
}

extern "C" void kernel_launch(void* const* d_in, const int* in_sizes, int n_in,
                              void* d_out, int out_size, void* d_ws, size_t ws_size,
                              hipStream_t stream) {
    (void)in_sizes; (void)n_in; (void)out_size; (void)ws_size;
    const float* x        = (const float*)d_in[0];
    const float* w_x2i    = (const float*)d_in[1];
    const float* b_x2i    = (const float*)d_in[2];
    const float* gru_wih  = (const float*)d_in[3];
    const float* gru_whh  = (const float*)d_in[4];
    const float* gru_bih  = (const float*)d_in[5];
    const float* gru_bhh  = (const float*)d_in[6];
    const float* wq_w     = (const float*)d_in[7];
    const float* wq_b     = (const float*)d_in[8];
    const float* wk_w     = (const float*)d_in[9];
    const float* wk_b     = (const float*)d_in[10];
    const float* gcn_w[3]  = {(const float*)d_in[11], (const float*)d_in[15], (const float*)d_in[19]};
    const float* gcn_b[3]  = {(const float*)d_in[12], (const float*)d_in[16], (const float*)d_in[20]};
    const float* conv_w[3] = {(const float*)d_in[13], (const float*)d_in[17], (const float*)d_in[21]};
    const float* conv_b[3] = {(const float*)d_in[14], (const float*)d_in[18], (const float*)d_in[22]};
    const float* lout_w   = (const float*)d_in[23];
    const float* lout_b   = (const float*)d_in[24];
    float* out = (float*)d_out;
    float* ws  = (float*)d_ws;

    float* hT   = ws;                        // 131072
    float* u    = ws + 131072;               // 2048
    float* v    = ws + 133120;               // 2048
    float* bufA = ws + 135168;               // 4194304
    float* bufB = bufA + 4194304;            // 4194304  (ends 8523776)
    unsigned short* usb = (unsigned short*)(ws + 8523776);
    unsigned short* whT_hi  = usb;                 // 131072
    unsigned short* whT_lo  = usb + 131072;
    unsigned short* gwT1_hi = usb + 262144;        // 131072
    unsigned short* gwT1_lo = usb + 393216;
    unsigned short* gwT2_hi = usb + 524288;
    unsigned short* gwT2_lo = usb + 655360;
    unsigned short* cw1_hi  = usb + 786432;        // 12288
    unsigned short* cw1_lo  = usb + 798720;
    unsigned short* cw2_hi  = usb + 811008;        // 20480
    unsigned short* cw2_lo  = usb + 831488;
    unsigned short* cw3_hi  = usb + 851968;        // 28672
    unsigned short* cw3_lo  = usb + 880640;

    // tiny prep kernels
    prep_uv<<<dim3(32), dim3(256), 0, stream>>>(gcn_w[0], w_x2i, b_x2i, u, v);
    prep_gwT<<<dim3(32), dim3(256), 0, stream>>>(gcn_w[1], gwT1_hi, gwT1_lo);
    prep_gwT<<<dim3(32), dim3(256), 0, stream>>>(gcn_w[2], gwT2_hi, gwT2_lo);
    prep_cw<<<dim3(64), dim3(256), 0, stream>>>(conv_w[0], cw1_hi, cw1_lo, 3);
    prep_cw<<<dim3(64), dim3(256), 0, stream>>>(conv_w[1], cw2_hi, cw2_lo, 5);
    prep_cw<<<dim3(64), dim3(256), 0, stream>>>(conv_w[2], cw3_hi, cw3_lo, 7);

    gru_kernel<<<dim3(512), dim3(256), 0, stream>>>(x, gru_wih, gru_whh, gru_bih, gru_bhh, hT);
    attn_kernel<<<dim3(32), dim3(256), 0, stream>>>(hT, wq_w, wq_b, wk_w, wk_b, whT_hi, whT_lo);

    gcn_mfma<true><<<dim3(1024), dim3(256), 0, stream>>>(x, nullptr, nullptr, u, v,
                                                         whT_hi, whT_lo, gcn_b[0], bufA);
    conv_mfma<3><<<dim3(2048), dim3(256), 0, stream>>>(bufA, cw1_hi, cw1_lo, conv_b[0]);
    gcn_mfma<false><<<dim3(1024), dim3(256), 0, stream>>>(bufA, gwT1_hi, gwT1_lo, u, v,
                                                          whT_hi, whT_lo, gcn_b[1], bufB);
    conv_mfma<5><<<dim3(2048), dim3(256), 0, stream>>>(bufB, cw2_hi, cw2_lo, conv_b[1]);
    gcn_mfma<false><<<dim3(1024), dim3(256), 0, stream>>>(bufB, gwT2_hi, gwT2_lo, u, v,
                                                          whT_hi, whT_lo, gcn_b[2], bufA);
    conv_mfma<7><<<dim3(2048), dim3(256), 0, stream>>>(bufA, cw3_hi, cw3_lo, conv_b[2]);

    unsigned short* flat16 = (unsigned short*)bufB;
    transpose_kernel<<<dim3(2048), dim3(256), 0, stream>>>(bufA, flat16);
    out_init<<<dim3(96), dim3(256), 0, stream>>>(lout_b, out);
    gemm_mfma<<<dim3(768), dim3(256), 0, stream>>>(flat16, lout_w, out);
}

// Round 5
// 307.756 us; speedup vs baseline: 3.2055x; 1.1207x over previous
//
#include <hip/hip_runtime.h>
#include <hip/hip_bf16.h>

// Problem constants
#define BB 32   // batch
#define TT 32   // window
#define NN 64   // num_series
#define CC 64   // inter_dim
#define HH 64   // gru hidden
#define QKD 32  // qk dim
#define HOR 12
#define OUTD (NN*HOR)        // 768
#define KFLAT (NN*CC*TT)     // 131072

typedef __attribute__((ext_vector_type(4))) float f32x4;
typedef __attribute__((ext_vector_type(8))) short s16x8;

// round-to-nearest-even fp32 -> bf16 (bit trick)
static __device__ __forceinline__ unsigned short f2bf(float f) {
    unsigned u = __float_as_uint(f);
    unsigned r = (u + 0x7FFFu + ((u >> 16) & 1u)) >> 16;
    return (unsigned short)r;
}
static __device__ __forceinline__ float bf2f(unsigned short h) {
    return __uint_as_float(((unsigned)h) << 16);
}
// split 8 fp32 -> 8 bf16 hi + 8 bf16 lo, packed as uint4 each
static __device__ __forceinline__ void split8(const float* f, uint4& hi, uint4& lo) {
    unsigned hh[8], ll[8];
    #pragma unroll
    for (int i = 0; i < 8; ++i) {
        unsigned short h = f2bf(f[i]);
        float hf = bf2f(h);
        hh[i] = h;
        ll[i] = f2bf(f[i] - hf);
    }
    hi = make_uint4(hh[0] | (hh[1] << 16), hh[2] | (hh[3] << 16),
                    hh[4] | (hh[5] << 16), hh[6] | (hh[7] << 16));
    lo = make_uint4(ll[0] | (ll[1] << 16), ll[2] | (ll[3] << 16),
                    ll[4] | (ll[5] << 16), ll[6] | (ll[7] << 16));
}
// async global->LDS, 16 bytes per lane; dest = wave-uniform base + lane*16
static __device__ __forceinline__ void gl2lds16(const void* gsrc, void* ldst) {
    __builtin_amdgcn_global_load_lds(
        (const __attribute__((address_space(1))) unsigned int*)gsrc,
        (__attribute__((address_space(3))) unsigned int*)ldst, 16, 0, 0);
}

// ---------------- GRU: wave-specialized k-chunks, Whh in registers ---------
__global__ __launch_bounds__(256) void gru_kernel(
    const float* __restrict__ x, const float* __restrict__ wih,
    const float* __restrict__ whh, const float* __restrict__ bih,
    const float* __restrict__ bhh, float* __restrict__ hT)
{
    __shared__ float Wt[64][193];          // Wt[k][G] = whh[G][k]; 193 kills write conflicts
    __shared__ float hbuf[4][64];
    __shared__ float part[4][4][3][64];    // [kchunk-wave][series][gate][j]
    int tid = threadIdx.x;
    for (int idx = tid; idx < 192*64; idx += 256) {
        int g = idx >> 6, k = idx & 63;
        Wt[k][g] = whh[idx];
    }
    int w = tid >> 6;            // wave id: k-chunk owner AND series owner
    int j = tid & 63;
    hbuf[w][j] = 0.0f;
    __syncthreads();
    float Wreg[3][16];
    #pragma unroll
    for (int g = 0; g < 3; ++g)
        #pragma unroll
        for (int kk = 0; kk < 16; ++kk)
            Wreg[g][kk] = Wt[w*16 + kk][g*64 + j];
    int gs0 = blockIdx.x * 4;
    int b = gs0 >> 6, n0 = gs0 & 63;
    float wih_r = wih[j], wih_z = wih[64+j], wih_n = wih[128+j];
    float bi_r = bih[j], bi_z = bih[64+j], bi_n = bih[128+j];
    float bh_r = bhh[j], bh_z = bhh[64+j], bh_n = bhh[128+j];
    float hreg = 0.0f;
    for (int t = 0; t < TT; ++t) {
        float p[3][4];
        #pragma unroll
        for (int g = 0; g < 3; ++g)
            #pragma unroll
            for (int s = 0; s < 4; ++s) p[g][s] = 0.f;
        #pragma unroll
        for (int s = 0; s < 4; ++s) {
            #pragma unroll
            for (int q = 0; q < 4; ++q) {
                const float4 hv = *(const float4*)&hbuf[s][w*16 + q*4];
                #pragma unroll
                for (int g = 0; g < 3; ++g) {
                    p[g][s] += hv.x*Wreg[g][q*4]   + hv.y*Wreg[g][q*4+1]
                             + hv.z*Wreg[g][q*4+2] + hv.w*Wreg[g][q*4+3];
                }
            }
        }
        #pragma unroll
        for (int g = 0; g < 3; ++g)
            #pragma unroll
            for (int s = 0; s < 4; ++s)
                part[w][s][g][j] = p[g][s];
        __syncthreads();
        float gr = bh_r + part[0][w][0][j] + part[1][w][0][j] + part[2][w][0][j] + part[3][w][0][j];
        float gz = bh_z + part[0][w][1][j] + part[1][w][1][j] + part[2][w][1][j] + part[3][w][1][j];
        float gn = bh_n + part[0][w][2][j] + part[1][w][2][j] + part[2][w][2][j] + part[3][w][2][j];
        float xt = x[(b*TT + t)*NN + n0 + w];
        float r = 1.f/(1.f+__expf(-(xt*wih_r + bi_r + gr)));
        float z = 1.f/(1.f+__expf(-(xt*wih_z + bi_z + gz)));
        float nn_ = tanhf(xt*wih_n + bi_n + r*gn);
        float hnew = (1.f - z)*nn_ + z*hreg;
        hreg = hnew;
        hbuf[w][j] = hnew;
        __syncthreads();
    }
    hT[(gs0 + w)*64 + j] = hreg;
}

// ---------------- attention -> WhatT hi/lo bf16 (per batch) ----------------
__global__ __launch_bounds__(256) void attn_kernel(
    const float* __restrict__ hT, const float* __restrict__ wq_w,
    const float* __restrict__ wq_b, const float* __restrict__ wk_w,
    const float* __restrict__ wk_b,
    unsigned short* __restrict__ whT_hi, unsigned short* __restrict__ whT_lo)
{
    __shared__ float hs[64][64];
    __shared__ float Qs[64][33], Ks[64][33];   // pad: kill Ks[m][q] bank conflicts
    __shared__ float S[64][65];                // pad: kill stride-64 conflicts
    __shared__ float pd[4][64];
    __shared__ float dinv[64];
    int b = blockIdx.x, tid = threadIdx.x;
    for (int idx = tid; idx < 64*64; idx += 256) hs[idx>>6][idx&63] = hT[b*4096 + idx];
    __syncthreads();
    for (int idx = tid; idx < 64*32; idx += 256) {
        int n_ = idx >> 5, q = idx & 31;
        float accq = wq_b[q], acck = wk_b[q];
        #pragma unroll 8
        for (int h_ = 0; h_ < 64; ++h_) {
            float hv = hs[n_][h_];
            accq += hv * wq_w[q*64 + h_];
            acck += hv * wk_w[q*64 + h_];
        }
        Qs[n_][q] = accq; Ks[n_][q] = acck;
    }
    __syncthreads();
    const float scale = 0.17677669529663687f; // 1/sqrt(32)
    for (int idx = tid; idx < 64*64; idx += 256) {
        int n_ = idx >> 6, m = idx & 63;
        float acc = 0.f;
        #pragma unroll 8
        for (int q = 0; q < 32; ++q) acc += Qs[n_][q]*Ks[m][q];
        S[n_][m] = acc * scale;
    }
    __syncthreads();
    {   // row softmax: 4 lanes per row
        int r = tid >> 2, q = tid & 3;
        float mx = -1e30f;
        #pragma unroll
        for (int m = 0; m < 16; ++m) mx = fmaxf(mx, S[r][q*16+m]);
        mx = fmaxf(mx, __shfl_xor(mx, 1));
        mx = fmaxf(mx, __shfl_xor(mx, 2));
        float sum = 0.f;
        float e[16];
        #pragma unroll
        for (int m = 0; m < 16; ++m) { e[m] = __expf(S[r][q*16+m]-mx); sum += e[m]; }
        sum += __shfl_xor(sum, 1);
        sum += __shfl_xor(sum, 2);
        float inv = 1.f/sum;
        #pragma unroll
        for (int m = 0; m < 16; ++m) S[r][q*16+m] = e[m]*inv;
    }
    __syncthreads();
    {   // column degree: partial sums over 16-row stripes
        int c = tid & 63, rq = tid >> 6;
        float d = 0.f;
        #pragma unroll
        for (int i = 0; i < 16; ++i) d += S[rq*16 + i][c];
        pd[rq][c] = d;
    }
    __syncthreads();
    if (tid < 64) {
        float d = pd[0][tid]+pd[1][tid]+pd[2][tid]+pd[3][tid];
        dinv[tid] = (d > 0.f) ? 1.0f/sqrtf(d) : 0.f;
    }
    __syncthreads();
    // WhatT[j][i] = dinv[i]*S[i][j]*dinv[j], split hi/lo
    for (int idx = tid; idx < 64*64; idx += 256) {
        int jj = idx >> 6, ii = idx & 63;
        float val = dinv[ii]*S[ii][jj]*dinv[jj];
        unsigned short h = f2bf(val);
        whT_hi[b*4096 + idx] = h;
        whT_lo[b*4096 + idx] = f2bf(val - bf2f(h));
    }
}

// ---------------- mega-prep: uv + gwT x2 + cw x3 + out_init ----------------
__global__ __launch_bounds__(256) void prep_all(
    const float* __restrict__ gw0, const float* __restrict__ wx, const float* __restrict__ bx,
    float* __restrict__ u, float* __restrict__ v,
    const float* __restrict__ gw1, unsigned short* __restrict__ g1h, unsigned short* __restrict__ g1l,
    const float* __restrict__ gw2, unsigned short* __restrict__ g2h, unsigned short* __restrict__ g2l,
    const float* __restrict__ cw1, unsigned short* __restrict__ c1h, unsigned short* __restrict__ c1l,
    const float* __restrict__ cw2, unsigned short* __restrict__ c2h, unsigned short* __restrict__ c2l,
    const float* __restrict__ cw3, unsigned short* __restrict__ c3h, unsigned short* __restrict__ c3l,
    const float* __restrict__ lb, float* __restrict__ out)
{
    int bid = blockIdx.x, tid = threadIdx.x;
    if (bid < 32) {                      // prep_uv, t=bid
        __shared__ float pu[4][64], pv[4][64];
        int t = bid, d = tid & 63, cq = tid >> 6;
        float su = 0.f, sv = 0.f;
        for (int c = cq*16; c < cq*16 + 16; ++c) {
            float gv = gw0[t*4096 + c*64 + d];
            su += wx[c]*gv; sv += bx[c]*gv;
        }
        pu[cq][d] = su; pv[cq][d] = sv;
        __syncthreads();
        if (tid < 64) {
            u[t*64 + tid] = pu[0][tid]+pu[1][tid]+pu[2][tid]+pu[3][tid];
            v[t*64 + tid] = pv[0][tid]+pv[1][tid]+pv[2][tid]+pv[3][tid];
        }
    } else if (bid < 96) {               // gwT for gw1/gw2
        const float* gw = (bid < 64) ? gw1 : gw2;
        unsigned short* hi = (bid < 64) ? g1h : g2h;
        unsigned short* lo = (bid < 64) ? g1l : g2l;
        int t = (bid < 64) ? bid - 32 : bid - 64;
        for (int idx = tid; idx < 4096; idx += 256) {
            int d = idx >> 6, c = idx & 63;
            float val = gw[t*4096 + c*64 + d];
            unsigned short h = f2bf(val);
            hi[t*4096 + idx] = h;
            lo[t*4096 + idx] = f2bf(val - bf2f(h));
        }
    } else if (bid < 288) {              // cw: [co][ka*64+ci] hi/lo
        const float* cw; unsigned short *hi, *lo; int KW, co;
        if (bid < 160)      { cw = cw1; hi = c1h; lo = c1l; KW = 3; co = bid - 96; }
        else if (bid < 224) { cw = cw2; hi = c2h; lo = c2l; KW = 5; co = bid - 160; }
        else                { cw = cw3; hi = c3h; lo = c3l; KW = 7; co = bid - 224; }
        int K = KW*64;
        for (int idx = tid; idx < K; idx += 256) {
            int ka = idx >> 6, ci = idx & 63;
            float val = cw[(size_t)(co*64 + ci)*KW + ka];
            unsigned short h = f2bf(val);
            hi[(size_t)co*K + idx] = h;
            lo[(size_t)co*K + idx] = f2bf(val - bf2f(h));
        }
    } else {                             // out_init: 96 blocks
        int idx = (bid - 288)*256 + tid;
        out[idx] = lb[idx % OUTD];
    }
}

// ---------------- GCN via MFMA (hi/lo split, fp32-class precision) ---------
template<bool FIRST>
__global__ __launch_bounds__(256) void gcn_mfma(
    const float* __restrict__ fin,
    const unsigned short* __restrict__ gwT_hi, const unsigned short* __restrict__ gwT_lo,
    const float* __restrict__ u, const float* __restrict__ v,
    const unsigned short* __restrict__ whT_hi, const unsigned short* __restrict__ whT_lo,
    const float* __restrict__ gb, float* __restrict__ o)
{
    __shared__ __align__(16) unsigned short ft_hi[64][64], ft_lo[64][64];
    __shared__ __align__(16) unsigned short xsT_hi[64][64], xsT_lo[64][64];
    __shared__ float x_l[64];
    int tb = blockIdx.x, t = tb >> 5, b = tb & 31;
    int tid = threadIdx.x;
    int w = tid >> 6, l = tid & 63, lm = l & 15, ld = l >> 4;

    if (FIRST) {
        if (tid < 64) x_l[tid] = fin[(b*TT + t)*NN + tid];
        __syncthreads();
        int d = tid >> 2, nq = tid & 3;
        float ud = u[t*64 + d], vd = v[t*64 + d];
        float vals[16];
        #pragma unroll
        for (int i = 0; i < 16; ++i) vals[i] = x_l[nq*16 + i]*ud + vd;
        #pragma unroll
        for (int h = 0; h < 2; ++h) {
            uint4 hi, lo; split8(&vals[h*8], hi, lo);
            int un = (nq*2 + h) ^ (d & 7);
            *(uint4*)&xsT_hi[d][un*8] = hi;
            *(uint4*)&xsT_lo[d][un*8] = lo;
        }
        __syncthreads();
    } else {
        {
            int row = tid >> 2, c0 = (tid & 3) * 16;
            const float* src = fin + (size_t)tb*4096 + row*64 + c0;
            float f8a[8], f8b[8];
            *(float4*)f8a = *(const float4*)src;       *(float4*)(f8a+4) = *(const float4*)(src+4);
            *(float4*)f8b = *(const float4*)(src+8);   *(float4*)(f8b+4) = *(const float4*)(src+12);
            uint4 hi, lo;
            split8(f8a, hi, lo);
            int u0 = ((c0>>3)) ^ (row & 7);
            *(uint4*)&ft_hi[row][u0*8] = hi; *(uint4*)&ft_lo[row][u0*8] = lo;
            split8(f8b, hi, lo);
            int u1 = ((c0>>3)+1) ^ (row & 7);
            *(uint4*)&ft_hi[row][u1*8] = hi; *(uint4*)&ft_lo[row][u1*8] = lo;
        }
        __syncthreads();
        f32x4 acc[4];
        #pragma unroll
        for (int ct = 0; ct < 4; ++ct) acc[ct] = (f32x4){0.f,0.f,0.f,0.f};
        #pragma unroll
        for (int kc = 0; kc < 2; ++kc) {
            int nrow = w*16 + lm;
            int ux = (kc*4 + ld) ^ (nrow & 7);
            s16x8 xh = *(const s16x8*)&ft_hi[nrow][ux*8];
            s16x8 xl = *(const s16x8*)&ft_lo[nrow][ux*8];
            #pragma unroll
            for (int ct = 0; ct < 4; ++ct) {
                int drow = ct*16 + lm;
                s16x8 yh = *(const s16x8*)&gwT_hi[t*4096 + drow*64 + kc*32 + ld*8];
                s16x8 yl = *(const s16x8*)&gwT_lo[t*4096 + drow*64 + kc*32 + ld*8];
                acc[ct] = __builtin_amdgcn_mfma_f32_16x16x32_bf16(xh, yh, acc[ct], 0, 0, 0);
                acc[ct] = __builtin_amdgcn_mfma_f32_16x16x32_bf16(xh, yl, acc[ct], 0, 0, 0);
                acc[ct] = __builtin_amdgcn_mfma_f32_16x16x32_bf16(xl, yh, acc[ct], 0, 0, 0);
            }
        }
        #pragma unroll
        for (int ct = 0; ct < 4; ++ct) {
            int d = ct*16 + lm;
            int n0 = w*16 + ld*4;
            unsigned short hh[4], llo[4];
            #pragma unroll
            for (int r = 0; r < 4; ++r) {
                float val = acc[ct][r];
                unsigned short h = f2bf(val);
                hh[r] = h; llo[r] = f2bf(val - bf2f(h));
            }
            int un = (n0 >> 3) ^ (d & 7);
            int base = d*64 + un*8 + (n0 & 7);
            *(uint2*)&xsT_hi[0][0 + base] = make_uint2(hh[0]|(hh[1]<<16), hh[2]|(hh[3]<<16));
            *(uint2*)&xsT_lo[0][0 + base] = make_uint2(llo[0]|(llo[1]<<16), llo[2]|(llo[3]<<16));
        }
        __syncthreads();
    }

    f32x4 acc2[4];
    #pragma unroll
    for (int ct = 0; ct < 4; ++ct) acc2[ct] = (f32x4){0.f,0.f,0.f,0.f};
    #pragma unroll
    for (int kc = 0; kc < 2; ++kc) {
        int jrow = w*16 + lm;
        s16x8 wh = *(const s16x8*)&whT_hi[b*4096 + jrow*64 + kc*32 + ld*8];
        s16x8 wl = *(const s16x8*)&whT_lo[b*4096 + jrow*64 + kc*32 + ld*8];
        #pragma unroll
        for (int ct = 0; ct < 4; ++ct) {
            int drow = ct*16 + lm;
            int uy = (kc*4 + ld) ^ (drow & 7);
            s16x8 yh = *(const s16x8*)&xsT_hi[drow][uy*8];
            s16x8 yl = *(const s16x8*)&xsT_lo[drow][uy*8];
            acc2[ct] = __builtin_amdgcn_mfma_f32_16x16x32_bf16(wh, yh, acc2[ct], 0, 0, 0);
            acc2[ct] = __builtin_amdgcn_mfma_f32_16x16x32_bf16(wh, yl, acc2[ct], 0, 0, 0);
            acc2[ct] = __builtin_amdgcn_mfma_f32_16x16x32_bf16(wl, yh, acc2[ct], 0, 0, 0);
        }
    }
    float* oo = o + (size_t)tb*4096;
    #pragma unroll
    for (int ct = 0; ct < 4; ++ct) {
        int d = ct*16 + lm;
        float bias = gb[t*64 + d];
        #pragma unroll
        for (int r = 0; r < 4; ++r) {
            int jj = w*16 + ld*4 + r;
            oo[jj*64 + d] = acc2[ct][r] + bias;
        }
    }
}

// ---------------- temporal conv1d via im2col MFMA + LeakyReLU --------------
// LAST: write bf16 flat (B, n*C*T + c*T + t) instead of fp32 in-place.
template<int KW, bool LAST>
__global__ __launch_bounds__(256) void conv_mfma(float* __restrict__ g,
    const unsigned short* __restrict__ wch, const unsigned short* __restrict__ wcl,
    const float* __restrict__ cb, unsigned short* __restrict__ fo)
{
    constexpr int P = KW/2, K = KW*64, K32 = KW*2;
    __shared__ __align__(16) unsigned short sh[32][64], sl[32][64];
    int bn = blockIdx.x, tid = threadIdx.x;
    {
        int t = tid >> 3, c0 = (tid & 7) * 8;
        const float* src = &g[((size_t)t*2048 + bn)*64 + c0];
        float f8[8];
        *(float4*)f8 = *(const float4*)src;
        *(float4*)(f8+4) = *(const float4*)(src+4);
        uint4 hi, lo; split8(f8, hi, lo);
        int uu = (tid & 7) ^ (t & 7);
        *(uint4*)&sh[t][uu*8] = hi;
        *(uint4*)&sl[t][uu*8] = lo;
    }
    __syncthreads();
    int w = tid >> 6, l = tid & 63, lm = l & 15, ld = l >> 4;
    int co = w*16 + lm;
    f32x4 acc0 = {0.f,0.f,0.f,0.f}, acc1 = {0.f,0.f,0.f,0.f};
    const s16x8 zf = {0,0,0,0,0,0,0,0};
    for (int kc = 0; kc < K32; ++kc) {
        int ka = kc >> 1;
        int ci = (kc & 1)*32 + ld*8;
        s16x8 yh = *(const s16x8*)&wch[(size_t)co*K + kc*32 + ld*8];
        s16x8 yl = *(const s16x8*)&wcl[(size_t)co*K + kc*32 + ld*8];
        #pragma unroll
        for (int Mt = 0; Mt < 2; ++Mt) {
            int ts = Mt*16 + lm + ka - P;
            bool ok = ((unsigned)ts) < 32u;
            int tc = ok ? ts : 0;
            int ua = (ci >> 3) ^ (tc & 7);
            s16x8 xh = *(const s16x8*)&sh[tc][ua*8];
            s16x8 xl = *(const s16x8*)&sl[tc][ua*8];
            if (!ok) { xh = zf; xl = zf; }
            f32x4& a = Mt ? acc1 : acc0;
            a = __builtin_amdgcn_mfma_f32_16x16x32_bf16(xh, yh, a, 0, 0, 0);
            a = __builtin_amdgcn_mfma_f32_16x16x32_bf16(xh, yl, a, 0, 0, 0);
            a = __builtin_amdgcn_mfma_f32_16x16x32_bf16(xl, yh, a, 0, 0, 0);
        }
    }
    float bias = cb[co];
    if (LAST) {
        int b = bn >> 6, n = bn & 63;
        unsigned short* ob = fo + (size_t)b*KFLAT + n*2048 + co*32;
        #pragma unroll
        for (int Mt = 0; Mt < 2; ++Mt) {
            const f32x4& a = Mt ? acc1 : acc0;
            unsigned short hv[4];
            #pragma unroll
            for (int r = 0; r < 4; ++r) {
                float val = a[r] + bias;
                val = (val >= 0.f) ? val : 0.01f*val;
                hv[r] = f2bf(val);
            }
            *(uint2*)&ob[Mt*16 + ld*4] = make_uint2(hv[0]|(hv[1]<<16), hv[2]|(hv[3]<<16));
        }
    } else {
        #pragma unroll
        for (int Mt = 0; Mt < 2; ++Mt) {
            const f32x4& a = Mt ? acc1 : acc0;
            #pragma unroll
            for (int r = 0; r < 4; ++r) {
                int t = Mt*16 + ld*4 + r;
                float val = a[r] + bias;
                val = (val >= 0.f) ? val : 0.01f*val;
                g[((size_t)t*2048 + bn)*64 + co] = val;
            }
        }
    }
}

// ---------------- final GEMM via MFMA, async LDS staging, counted vmcnt ----
// out[b][o] += sum_k flat[b][k] * W[o][k].  Grid: 12 o-groups x 64 k-chunks.
// Per block: 64o x 32b x 2048k. Double-buffered LDS tiles staged with
// global_load_lds (linear dest, swizzle folded into per-lane global src).
// 2-tile-deep pipeline, vmcnt(5) counted waits (5 loads/tile/wave).
__global__ __launch_bounds__(256) void gemm_mfma(const unsigned short* __restrict__ flat,
                                                 const float* __restrict__ W,
                                                 float* __restrict__ out)
{
    __shared__ __align__(16) float Wl[2][64][64];            // 32 KB
    __shared__ __align__(16) unsigned short Al[2][32][64];   // 8 KB
    const int tid = threadIdx.x;
    const int w = tid >> 6, l = tid & 63;
    const int og = blockIdx.x >> 6;        // 0..11
    const int kc = blockIdx.x & 63;        // 0..63 (same kc -> same XCD: bid%8==kc%8)
    const int o_blk = og * 64;
    const int kbase = kc * 2048;

    // W staging: wave w owns rows w*16..w*16+15; instr i covers 4 rows.
    const int wrow_l = l >> 4;             // row within instr
    const int wu = l & 15;                 // 16B unit within row
    size_t w_off[4];
    #pragma unroll
    for (int i = 0; i < 4; ++i) {
        int row = w*16 + i*4 + wrow_l;
        w_off[i] = (size_t)(o_blk + row) * KFLAT + (unsigned)((wu ^ (row & 7)) * 4);
    }
    // A staging: wave w owns rows w*8..w*8+7 (1 instr, 16B units).
    const int arow = w*8 + (l >> 3);
    const int au = l & 7;
    const size_t a_off0 = (size_t)arow * KFLAT + (unsigned)((au ^ (arow & 7)) * 8);

#define ISSUE_TILE(buf_, s_) { \
    int kwin_ = kbase + (s_)*64; \
    _Pragma("unroll") \
    for (int i_ = 0; i_ < 4; ++i_) \
        gl2lds16(W + w_off[i_] + kwin_, &Wl[buf_][w*16 + i_*4][0]); \
    gl2lds16(flat + a_off0 + kwin_, &Al[buf_][w*8][0]); \
}

    f32x4 acc0 = {0.f,0.f,0.f,0.f}, acc1 = {0.f,0.f,0.f,0.f};
    ISSUE_TILE(0, 0);
    ISSUE_TILE(1, 1);

    const int lmod = l & 15, ldiv = l >> 4, lx = l & 7;
    for (int s = 0; s < 32; ++s) {
        if (s < 31) { asm volatile("s_waitcnt vmcnt(5)" ::: "memory"); }
        else        { asm volatile("s_waitcnt vmcnt(0)" ::: "memory"); }
        __builtin_amdgcn_s_barrier();
        asm volatile("" ::: "memory");
        const int cur = s & 1;
        #pragma unroll
        for (int ksub = 0; ksub < 2; ++ksub) {
            int ju = ksub*8 + ldiv*2;
            const float4 b0 = *(const float4*)&Wl[cur][w*16 + lmod][(ju ^ lx)*4];
            const float4 b1 = *(const float4*)&Wl[cur][w*16 + lmod][((ju+1) ^ lx)*4];
            float bf[8] = {b0.x,b0.y,b0.z,b0.w,b1.x,b1.y,b1.z,b1.w};
            s16x8 bhi, blo;
            #pragma unroll
            for (int i = 0; i < 8; ++i) {
                unsigned short h = f2bf(bf[i]);
                float hf = bf2f(h);
                bhi[i] = (short)h;
                blo[i] = (short)f2bf(bf[i] - hf);
            }
            int jua = ksub*4 + ldiv;
            const s16x8 a0 = *(const s16x8*)&Al[cur][lmod]      [(jua ^ lx)*8];
            const s16x8 a1 = *(const s16x8*)&Al[cur][16 + lmod] [(jua ^ lx)*8];
            acc0 = __builtin_amdgcn_mfma_f32_16x16x32_bf16(a0, bhi, acc0, 0, 0, 0);
            acc0 = __builtin_amdgcn_mfma_f32_16x16x32_bf16(a0, blo, acc0, 0, 0, 0);
            acc1 = __builtin_amdgcn_mfma_f32_16x16x32_bf16(a1, bhi, acc1, 0, 0, 0);
            acc1 = __builtin_amdgcn_mfma_f32_16x16x32_bf16(a1, blo, acc1, 0, 0, 0);
        }
        asm volatile("" ::: "memory");
        __builtin_amdgcn_s_barrier();
        if (s < 30) { ISSUE_TILE(cur, s+2); }
    }
#undef ISSUE_TILE

    const int o_out = o_blk + w*16 + lmod;
    #pragma unroll
    for (int r = 0; r < 4; ++r) {
        int b0_ = ldiv*4 + r;
        atomicAdd(&out[(size_t)b0_*OUTD + o_out], acc0[r]);
        atomicAdd(&out[(size_t)(16 + b0_)*OUTD + o_out], acc1[r]);
    }
}

extern "C" void kernel_launch(void* const* d_in, const int* in_sizes, int n_in,
                              void* d_out, int out_size, void* d_ws, size_t ws_size,
                              hipStream_t stream) {
    (void)in_sizes; (void)n_in; (void)out_size; (void)ws_size;
    const float* x        = (const float*)d_in[0];
    const float* w_x2i    = (const float*)d_in[1];
    const float* b_x2i    = (const float*)d_in[2];
    const float* gru_wih  = (const float*)d_in[3];
    const float* gru_whh  = (const float*)d_in[4];
    const float* gru_bih  = (const float*)d_in[5];
    const float* gru_bhh  = (const float*)d_in[6];
    const float* wq_w     = (const float*)d_in[7];
    const float* wq_b     = (const float*)d_in[8];
    const float* wk_w     = (const float*)d_in[9];
    const float* wk_b     = (const float*)d_in[10];
    const float* gcn_w[3]  = {(const float*)d_in[11], (const float*)d_in[15], (const float*)d_in[19]};
    const float* gcn_b[3]  = {(const float*)d_in[12], (const float*)d_in[16], (const float*)d_in[20]};
    const float* conv_w[3] = {(const float*)d_in[13], (const float*)d_in[17], (const float*)d_in[21]};
    const float* conv_b[3] = {(const float*)d_in[14], (const float*)d_in[18], (const float*)d_in[22]};
    const float* lout_w   = (const float*)d_in[23];
    const float* lout_b   = (const float*)d_in[24];
    float* out = (float*)d_out;
    float* ws  = (float*)d_ws;

    float* hT   = ws;                        // 131072
    float* u    = ws + 131072;               // 2048
    float* v    = ws + 133120;               // 2048
    float* bufA = ws + 135168;               // 4194304
    float* bufB = bufA + 4194304;            // 4194304  (ends 8523776)
    unsigned short* usb = (unsigned short*)(ws + 8523776);
    unsigned short* whT_hi  = usb;                 // 131072
    unsigned short* whT_lo  = usb + 131072;
    unsigned short* gwT1_hi = usb + 262144;        // 131072
    unsigned short* gwT1_lo = usb + 393216;
    unsigned short* gwT2_hi = usb + 524288;
    unsigned short* gwT2_lo = usb + 655360;
    unsigned short* cw1_hi  = usb + 786432;        // 12288
    unsigned short* cw1_lo  = usb + 798720;
    unsigned short* cw2_hi  = usb + 811008;        // 20480
    unsigned short* cw2_lo  = usb + 831488;
    unsigned short* cw3_hi  = usb + 851968;        // 28672
    unsigned short* cw3_lo  = usb + 880640;

    prep_all<<<dim3(384), dim3(256), 0, stream>>>(
        gcn_w[0], w_x2i, b_x2i, u, v,
        gcn_w[1], gwT1_hi, gwT1_lo,
        gcn_w[2], gwT2_hi, gwT2_lo,
        conv_w[0], cw1_hi, cw1_lo,
        conv_w[1], cw2_hi, cw2_lo,
        conv_w[2], cw3_hi, cw3_lo,
        lout_b, out);

    gru_kernel<<<dim3(512), dim3(256), 0, stream>>>(x, gru_wih, gru_whh, gru_bih, gru_bhh, hT);
    attn_kernel<<<dim3(32), dim3(256), 0, stream>>>(hT, wq_w, wq_b, wk_w, wk_b, whT_hi, whT_lo);

    unsigned short* flat16 = (unsigned short*)bufB;
    gcn_mfma<true><<<dim3(1024), dim3(256), 0, stream>>>(x, nullptr, nullptr, u, v,
                                                         whT_hi, whT_lo, gcn_b[0], bufA);
    conv_mfma<3,false><<<dim3(2048), dim3(256), 0, stream>>>(bufA, cw1_hi, cw1_lo, conv_b[0], nullptr);
    gcn_mfma<false><<<dim3(1024), dim3(256), 0, stream>>>(bufA, gwT1_hi, gwT1_lo, u, v,
                                                          whT_hi, whT_lo, gcn_b[1], bufB);
    conv_mfma<5,false><<<dim3(2048), dim3(256), 0, stream>>>(bufB, cw2_hi, cw2_lo, conv_b[1], nullptr);
    gcn_mfma<false><<<dim3(1024), dim3(256), 0, stream>>>(bufB, gwT2_hi, gwT2_lo, u, v,
                                                          whT_hi, whT_lo, gcn_b[2], bufA);
    conv_mfma<7,true><<<dim3(2048), dim3(256), 0, stream>>>(bufA, cw3_hi, cw3_lo, conv_b[2], (unsigned short*)bufB);

    gemm_mfma<<<dim3(768), dim3(256), 0, stream>>>(flat16, lout_w, out);
}